// Round 1
// baseline (1496.575 us; speedup 1.0000x reference)
//
#include <hip/hip_runtime.h>
#include <hip/hip_bf16.h>
#include <math.h>

#define NJ 30000
#define NS 12000
#define E_JS 300000
#define E_SJ 300000
#define E_SS 150000
#define E_SSL (E_SS + NS)   // ss edges + self loops = 162000
#define SBERT 384
#define HIDDEN 128
#define OUTD 128

static inline int cdiv(int a, int b) { return (a + b - 1) / b; }

// ---------------------------------------------------------------------------
// Utility kernels
// ---------------------------------------------------------------------------
__global__ void k_fill_f32(float* __restrict__ p, float v, int n) {
    int i = blockIdx.x * 256 + threadIdx.x;
    if (i < n) p[i] = v;
}
__global__ void k_fill_i32(int* __restrict__ p, int v, int n) {
    int i = blockIdx.x * 256 + threadIdx.x;
    if (i < n) p[i] = v;
}
__global__ void k_copy_i32(const int* __restrict__ a, int* __restrict__ b, int n) {
    int i = blockIdx.x * 256 + threadIdx.x;
    if (i < n) b[i] = a[i];
}

// concat ss edges with self loops
__global__ void k_concat_ss(const int* __restrict__ s, const int* __restrict__ d,
                            int* __restrict__ cs, int* __restrict__ cd) {
    int i = blockIdx.x * 256 + threadIdx.x;
    if (i < E_SS) { cs[i] = s[i]; cd[i] = d[i]; }
    else if (i < E_SSL) { int n = i - E_SS; cs[i] = n; cd[i] = n; }
}

// ---------------------------------------------------------------------------
// Precompute ws_a / wd_a : wa[l,r][k][h] = sum_c W[l,r][k][h*128+c] * a[l,r][h][c]
// ---------------------------------------------------------------------------
__global__ void k_wa(const float* __restrict__ Ws, const float* __restrict__ as,
                     const float* __restrict__ Wd, const float* __restrict__ ad,
                     float* __restrict__ wsa, float* __restrict__ wda) {
    int id = blockIdx.x * 256 + threadIdx.x;   // 2 * 1536 total
    if (id >= 2 * 1536) return;
    int which = id / 1536;
    int r = id % 1536;
    int lr = r / 256;       // 0..5  (l*3 + rel)
    int kh = r % 256;
    int k = kh / 2, h = kh % 2;
    const float* W = which ? Wd : Ws;
    const float* a = which ? ad : as;
    const float* wrow = W + ((size_t)(lr * 128 + k)) * 256 + h * 128;
    const float* arow = a + (size_t)(lr * 2 + h) * 128;
    float acc = 0.f;
    for (int c = 0; c < 128; ++c) acc += wrow[c] * arow[c];
    (which ? wda : wsa)[lr * 256 + k * 2 + h] = acc;
}

// ---------------------------------------------------------------------------
// Tiled fp32 GEMM: Y[M,TN] = X[M,K] @ W[K,TN]  (N == TN exactly)
// EPI: 0=none, 1=+bias, 2=+bias,relu, 3=+bias,LayerNorm,relu (TN must be 128)
// block=256 threads, micro-tile 8 rows x 4 cols per thread.
// ---------------------------------------------------------------------------
template <int TN, int EPI>
__global__ __launch_bounds__(256) void k_gemm(
    const float* __restrict__ X, const float* __restrict__ W,
    const float* __restrict__ bias, const float* __restrict__ gamma,
    const float* __restrict__ beta, float* __restrict__ Y, int M, int K) {
    constexpr int CX = TN / 4;       // threads along cols
    constexpr int TM = (256 / CX) * 8;
    constexpr int KC = 32;
    __shared__ float xT[KC][TM + 4];
    __shared__ float Wc[KC][TN];

    const int t = threadIdx.x;
    const int tx = t % CX, ty = t / CX;
    const int row0 = blockIdx.x * TM;

    float acc[8][4];
#pragma unroll
    for (int i = 0; i < 8; i++)
#pragma unroll
        for (int j = 0; j < 4; j++) acc[i][j] = 0.f;

    for (int k0 = 0; k0 < K; k0 += KC) {
#pragma unroll
        for (int it = 0; it < (TM * KC) / 256; ++it) {
            int idx = t + it * 256;
            int r = idx / KC, k = idx % KC;
            int grow = row0 + r;
            float v = (grow < M) ? X[(size_t)grow * K + k0 + k] : 0.f;
            xT[k][r] = v;
        }
#pragma unroll
        for (int it = 0; it < (KC * TN) / 1024; ++it) {
            int idx4 = t + it * 256;
            float4 w4 = *(const float4*)&W[(size_t)k0 * TN + idx4 * 4];
            *(float4*)&Wc[0][idx4 * 4] = w4;
        }
        __syncthreads();
#pragma unroll
        for (int k = 0; k < KC; ++k) {
            float4 b = *(const float4*)&Wc[k][tx * 4];
            float4 a0 = *(const float4*)&xT[k][ty * 8];
            float4 a1 = *(const float4*)&xT[k][ty * 8 + 4];
            float av[8] = {a0.x, a0.y, a0.z, a0.w, a1.x, a1.y, a1.z, a1.w};
#pragma unroll
            for (int i = 0; i < 8; i++) {
                acc[i][0] += av[i] * b.x;
                acc[i][1] += av[i] * b.y;
                acc[i][2] += av[i] * b.z;
                acc[i][3] += av[i] * b.w;
            }
        }
        __syncthreads();
    }

    const int col = tx * 4;
    float4 bb = make_float4(0.f, 0.f, 0.f, 0.f);
    if constexpr (EPI >= 1) bb = *(const float4*)&bias[col];

    if constexpr (EPI == 3) {
        static_assert(TN == 128, "LN epilogue needs full row in tile");
        float4 gg = *(const float4*)&gamma[col];
        float4 be4 = *(const float4*)&beta[col];
#pragma unroll
        for (int i = 0; i < 8; i++) {
            float v0 = acc[i][0] + bb.x, v1 = acc[i][1] + bb.y;
            float v2 = acc[i][2] + bb.z, v3 = acc[i][3] + bb.w;
            float s = v0 + v1 + v2 + v3;
            float q = v0 * v0 + v1 * v1 + v2 * v2 + v3 * v3;
#pragma unroll
            for (int msk = 16; msk >= 1; msk >>= 1) {
                s += __shfl_xor(s, msk, 64);
                q += __shfl_xor(q, msk, 64);
            }
            float mu = s * (1.0f / 128.0f);
            float var = q * (1.0f / 128.0f) - mu * mu;
            float rs = rsqrtf(var + 1e-5f);
            v0 = fmaxf((v0 - mu) * rs * gg.x + be4.x, 0.f);
            v1 = fmaxf((v1 - mu) * rs * gg.y + be4.y, 0.f);
            v2 = fmaxf((v2 - mu) * rs * gg.z + be4.z, 0.f);
            v3 = fmaxf((v3 - mu) * rs * gg.w + be4.w, 0.f);
            int grow = row0 + ty * 8 + i;
            if (grow < M) *(float4*)&Y[(size_t)grow * TN + col] = make_float4(v0, v1, v2, v3);
        }
    } else {
#pragma unroll
        for (int i = 0; i < 8; i++) {
            float v0 = acc[i][0] + bb.x, v1 = acc[i][1] + bb.y;
            float v2 = acc[i][2] + bb.z, v3 = acc[i][3] + bb.w;
            if constexpr (EPI == 2) {
                v0 = fmaxf(v0, 0.f); v1 = fmaxf(v1, 0.f);
                v2 = fmaxf(v2, 0.f); v3 = fmaxf(v3, 0.f);
            }
            int grow = row0 + ty * 8 + i;
            if (grow < M) *(float4*)&Y[(size_t)grow * TN + col] = make_float4(v0, v1, v2, v3);
        }
    }
}

// ---------------------------------------------------------------------------
// alpha[n,h] = sum_k x[n,k] * wa[k*2+h]   (K = 128, wave per node)
// ---------------------------------------------------------------------------
__global__ __launch_bounds__(256) void k_alpha(const float* __restrict__ x,
                                               const float* __restrict__ wa,
                                               float* __restrict__ out, int n) {
    int wave = threadIdx.x >> 6, lane = threadIdx.x & 63;
    int node = blockIdx.x * 4 + wave;
    if (node >= n) return;
    float2 xv = *(const float2*)&x[(size_t)node * 128 + lane * 2];
    float4 wv = *(const float4*)&wa[lane * 4];  // (k0,h0) (k0,h1) (k1,h0) (k1,h1)
    float p0 = xv.x * wv.x + xv.y * wv.z;
    float p1 = xv.x * wv.y + xv.y * wv.w;
#pragma unroll
    for (int m = 32; m >= 1; m >>= 1) {
        p0 += __shfl_xor(p0, m, 64);
        p1 += __shfl_xor(p1, m, 64);
    }
    if (lane == 0) { out[node * 2] = p0; out[node * 2 + 1] = p1; }
}

// ---------------------------------------------------------------------------
// Edge softmax passes
// ---------------------------------------------------------------------------
__device__ inline void atomicMaxFloat(float* addr, float v) {
    if (v >= 0.f) atomicMax((int*)addr, __float_as_int(v));
    else atomicMin((unsigned int*)addr, __float_as_uint(v));
}

__global__ void k_edge_max(const int* __restrict__ src, const int* __restrict__ dst,
                           const float* __restrict__ as, const float* __restrict__ ad,
                           float* __restrict__ ee, float* __restrict__ m, int E) {
    int e = blockIdx.x * 256 + threadIdx.x;
    if (e >= E) return;
    int s = src[e], d = dst[e];
    float2 a = *(const float2*)&as[(size_t)s * 2];
    float2 b = *(const float2*)&ad[(size_t)d * 2];
    float v0 = a.x + b.x; v0 = v0 > 0.f ? v0 : 0.2f * v0;
    float v1 = a.y + b.y; v1 = v1 > 0.f ? v1 : 0.2f * v1;
    ee[(size_t)e * 2] = v0; ee[(size_t)e * 2 + 1] = v1;
    atomicMaxFloat(&m[(size_t)d * 2], v0);
    atomicMaxFloat(&m[(size_t)d * 2 + 1], v1);
}

__global__ void k_edge_expsum(const int* __restrict__ dst, float* __restrict__ ee,
                              const float* __restrict__ m, float* __restrict__ den, int E) {
    int e = blockIdx.x * 256 + threadIdx.x;
    if (e >= E) return;
    int d = dst[e];
    float2 mm = *(const float2*)&m[(size_t)d * 2];
    float p0 = expf(ee[(size_t)e * 2] - mm.x);
    float p1 = expf(ee[(size_t)e * 2 + 1] - mm.y);
    ee[(size_t)e * 2] = p0; ee[(size_t)e * 2 + 1] = p1;
    atomicAdd(&den[(size_t)d * 2], p0);
    atomicAdd(&den[(size_t)d * 2 + 1], p1);
}

// ---------------------------------------------------------------------------
// CSR build
// ---------------------------------------------------------------------------
__global__ void k_hist(const int* __restrict__ dst, int* __restrict__ deg, int E) {
    int e = blockIdx.x * 256 + threadIdx.x;
    if (e < E) atomicAdd(&deg[dst[e]], 1);
}

__global__ void k_exscan(const int* __restrict__ deg, int* __restrict__ offs, int n) {
    __shared__ int sdata[1024];
    __shared__ int carry;
    if (threadIdx.x == 0) carry = 0;
    __syncthreads();
    for (int base = 0; base < n; base += 1024) {
        int i = base + (int)threadIdx.x;
        int v = (i < n) ? deg[i] : 0;
        sdata[threadIdx.x] = v;
        __syncthreads();
        for (int off = 1; off < 1024; off <<= 1) {
            int tmp = (threadIdx.x >= (unsigned)off) ? sdata[threadIdx.x - off] : 0;
            __syncthreads();
            sdata[threadIdx.x] += tmp;
            __syncthreads();
        }
        if (i < n) offs[i] = carry + sdata[threadIdx.x] - v;
        __syncthreads();
        if (threadIdx.x == 1023) carry += sdata[1023];
        __syncthreads();
    }
    if (threadIdx.x == 0) offs[n] = carry;
}

__global__ void k_scatter(const int* __restrict__ src, const int* __restrict__ dst,
                          int* __restrict__ cur, int* __restrict__ eid,
                          int* __restrict__ esrc, int E) {
    int e = blockIdx.x * 256 + threadIdx.x;
    if (e >= E) return;
    int d = dst[e];
    int pos = atomicAdd(&cur[d], 1);
    eid[pos] = e;
    esrc[pos] = src[e];
}

// ---------------------------------------------------------------------------
// Gather: out[d, :256] (+)= (sum_e p[e,h] * hs[src_e, :]) / (den[d,h]+eps) + bias
// wave per dst node, lane covers 4 cols.
// ---------------------------------------------------------------------------
__global__ __launch_bounds__(256) void k_gather(
    const int* __restrict__ offs, const int* __restrict__ eid, const int* __restrict__ esrc,
    const float* __restrict__ p, const float* __restrict__ hs, const float* __restrict__ den,
    const float* __restrict__ bias, float* __restrict__ out, int Nd, int accumulate) {
    int wave = threadIdx.x >> 6, lane = threadIdx.x & 63;
    int d = blockIdx.x * 4 + wave;
    if (d >= Nd) return;
    int c = lane * 4;
    bool h0 = c < 128;
    int beg = offs[d], end = offs[d + 1];
    float ax = 0.f, ay = 0.f, az = 0.f, aw = 0.f;
    for (int j = beg; j < end; ++j) {
        int e = eid[j];
        int s = esrc[j];
        float wgt = h0 ? p[(size_t)e * 2] : p[(size_t)e * 2 + 1];
        float4 hv = *(const float4*)&hs[(size_t)s * 256 + c];
        ax += wgt * hv.x; ay += wgt * hv.y; az += wgt * hv.z; aw += wgt * hv.w;
    }
    float dn = h0 ? den[(size_t)d * 2] : den[(size_t)d * 2 + 1];
    float sc = 1.f / (dn + 1e-16f);
    float4 b4 = *(const float4*)&bias[c];
    float* op = &out[(size_t)d * 256 + c];
    float4 o;
    if (accumulate) {
        o = *(float4*)op;
        o.x += ax * sc + b4.x; o.y += ay * sc + b4.y;
        o.z += az * sc + b4.z; o.w += aw * sc + b4.w;
    } else {
        o = make_float4(ax * sc + b4.x, ay * sc + b4.y, az * sc + b4.z, aw * sc + b4.w);
    }
    *(float4*)op = o;
}

// ---------------------------------------------------------------------------
// q = query @ Wq + bq
// ---------------------------------------------------------------------------
__global__ void k_qvec(const float* __restrict__ query, const float* __restrict__ Wq,
                       const float* __restrict__ bq, float* __restrict__ qv) {
    int c = threadIdx.x;  // 128
    float acc = bq[c];
    for (int k = 0; k < SBERT; ++k) acc += query[k] * Wq[(size_t)k * 128 + c];
    qv[c] = acc;
}

// scores[r] = job_emb[r] . q   (wave per row)
__global__ __launch_bounds__(256) void k_scores(const float* __restrict__ jemb,
                                                const float* __restrict__ q,
                                                float* __restrict__ sc, int n) {
    int wave = threadIdx.x >> 6, lane = threadIdx.x & 63;
    int r = blockIdx.x * 4 + wave;
    if (r >= n) return;
    float2 a = *(const float2*)&jemb[(size_t)r * 128 + lane * 2];
    float2 b = *(const float2*)&q[lane * 2];
    float p = a.x * b.x + a.y * b.y;
#pragma unroll
    for (int m = 32; m >= 1; m >>= 1) p += __shfl_xor(p, m, 64);
    if (lane == 0) sc[r] = p;
}

// ---------------------------------------------------------------------------
extern "C" void kernel_launch(void* const* d_in, const int* in_sizes, int n_in,
                              void* d_out, int out_size, void* d_ws, size_t ws_size,
                              hipStream_t stream) {
    const float* x_job   = (const float*)d_in[0];
    const float* x_skill = (const float*)d_in[1];
    const int* js_src = (const int*)d_in[2];
    const int* js_dst = (const int*)d_in[3];
    const int* sj_src = (const int*)d_in[4];
    const int* sj_dst = (const int*)d_in[5];
    const int* ss_src = (const int*)d_in[6];
    const int* ss_dst = (const int*)d_in[7];
    const float* query    = (const float*)d_in[8];
    const float* W0_job   = (const float*)d_in[9];
    const float* b0_job   = (const float*)d_in[10];
    const float* g0_job   = (const float*)d_in[11];
    const float* be0_job  = (const float*)d_in[12];
    const float* W0_skill = (const float*)d_in[13];
    const float* b0_skill = (const float*)d_in[14];
    const float* g0_skill = (const float*)d_in[15];
    const float* be0_skill= (const float*)d_in[16];
    const float* gat_Ws = (const float*)d_in[17];
    const float* gat_Wd = (const float*)d_in[18];
    const float* gat_as = (const float*)d_in[19];
    const float* gat_ad = (const float*)d_in[20];
    const float* gat_b  = (const float*)d_in[21];
    const float* inter_W = (const float*)d_in[22];
    const float* inter_b = (const float*)d_in[23];
    const float* Wjf = (const float*)d_in[24];
    const float* bjf = (const float*)d_in[25];
    const float* Wq  = (const float*)d_in[26];
    const float* bq  = (const float*)d_in[27];

    // workspace carve (256B aligned bump allocator)
    char* w = (char*)d_ws;
    auto alloc = [&](size_t bytes) -> void* {
        void* p = (void*)w;
        w += (bytes + 255) & ~(size_t)255;
        return p;
    };
    float* xj  = (float*)alloc((size_t)NJ * 128 * 4);
    float* xs  = (float*)alloc((size_t)NS * 128 * 4);
    float* hs  = (float*)alloc((size_t)NJ * 256 * 4);
    float* oj  = (float*)alloc((size_t)NJ * 256 * 4);
    float* os  = (float*)alloc((size_t)NS * 256 * 4);
    float* pbuf = (float*)alloc((size_t)E_JS * 2 * 4);
    float* asb = (float*)alloc((size_t)NJ * 2 * 4);
    float* adb = (float*)alloc((size_t)NJ * 2 * 4);
    float* mbuf = (float*)alloc((size_t)NJ * 2 * 4);
    float* den  = (float*)alloc((size_t)NJ * 2 * 4);
    float* wsa = (float*)alloc(6 * 256 * 4);
    float* wda = (float*)alloc(6 * 256 * 4);
    int* css = (int*)alloc((size_t)E_SSL * 4);
    int* csd = (int*)alloc((size_t)E_SSL * 4);
    int* offs_js = (int*)alloc((NS + 1) * 4);
    int* eid_js  = (int*)alloc((size_t)E_JS * 4);
    int* esrc_js = (int*)alloc((size_t)E_JS * 4);
    int* offs_sj = (int*)alloc((NJ + 1) * 4);
    int* eid_sj  = (int*)alloc((size_t)E_SJ * 4);
    int* esrc_sj = (int*)alloc((size_t)E_SJ * 4);
    int* offs_ss = (int*)alloc((NS + 1) * 4);
    int* eid_ss  = (int*)alloc((size_t)E_SSL * 4);
    int* esrc_ss = (int*)alloc((size_t)E_SSL * 4);
    int* deg = (int*)alloc((size_t)NJ * 4);
    int* cur = (int*)alloc((size_t)NJ * 4);

    float* out = (float*)d_out;
    float* scores  = out;
    float* job_emb = out + NJ;
    float* qv      = out + NJ + (size_t)NJ * 128;

    // --- precompute attention weight vectors ---
    k_wa<<<cdiv(2 * 1536, 256), 256, 0, stream>>>(gat_Ws, gat_as, gat_Wd, gat_ad, wsa, wda);

    // --- initial linear + LN + relu ---
    k_gemm<128, 3><<<cdiv(NJ, 64), 256, 0, stream>>>(x_job, W0_job, b0_job, g0_job, be0_job, xj, NJ, SBERT);
    k_gemm<128, 3><<<cdiv(NS, 64), 256, 0, stream>>>(x_skill, W0_skill, b0_skill, g0_skill, be0_skill, xs, NS, SBERT);

    // --- ss edges with self loops ---
    k_concat_ss<<<cdiv(E_SSL, 256), 256, 0, stream>>>(ss_src, ss_dst, css, csd);

    // --- CSR builds (layer-invariant) ---
    auto build_csr = [&](const int* srcA, const int* dstA, int E, int Nd,
                         int* offs, int* eid, int* esrc) {
        k_fill_i32<<<cdiv(Nd, 256), 256, 0, stream>>>(deg, 0, Nd);
        k_hist<<<cdiv(E, 256), 256, 0, stream>>>(dstA, deg, E);
        k_exscan<<<1, 1024, 0, stream>>>(deg, offs, Nd);
        k_copy_i32<<<cdiv(Nd, 256), 256, 0, stream>>>(offs, cur, Nd);
        k_scatter<<<cdiv(E, 256), 256, 0, stream>>>(srcA, dstA, cur, eid, esrc, E);
    };
    build_csr(js_src, js_dst, E_JS, NS, offs_js, eid_js, esrc_js);
    build_csr(sj_src, sj_dst, E_SJ, NJ, offs_sj, eid_sj, esrc_sj);
    build_csr(css, csd, E_SSL, NS, offs_ss, eid_ss, esrc_ss);

    auto run_gat = [&](const float* x_src, int Nsrc, const float* x_dst, int Nd, int lr,
                       const int* srcA, const int* dstA, int E,
                       const int* offs, const int* eid, const int* esrc,
                       float* outbuf, int accumulate) {
        k_gemm<256, 0><<<cdiv(Nsrc, 32), 256, 0, stream>>>(
            x_src, gat_Ws + (size_t)lr * 128 * 256, nullptr, nullptr, nullptr, hs, Nsrc, 128);
        k_alpha<<<cdiv(Nsrc, 4), 256, 0, stream>>>(x_src, wsa + lr * 256, asb, Nsrc);
        k_alpha<<<cdiv(Nd, 4), 256, 0, stream>>>(x_dst, wda + lr * 256, adb, Nd);
        k_fill_f32<<<cdiv(Nd * 2, 256), 256, 0, stream>>>(mbuf, -INFINITY, Nd * 2);
        k_fill_f32<<<cdiv(Nd * 2, 256), 256, 0, stream>>>(den, 0.f, Nd * 2);
        k_edge_max<<<cdiv(E, 256), 256, 0, stream>>>(srcA, dstA, asb, adb, pbuf, mbuf, E);
        k_edge_expsum<<<cdiv(E, 256), 256, 0, stream>>>(dstA, pbuf, mbuf, den, E);
        k_gather<<<cdiv(Nd, 4), 256, 0, stream>>>(offs, eid, esrc, pbuf, hs, den,
                                                  gat_b + (size_t)lr * 256, outbuf, Nd, accumulate);
    };

    for (int l = 0; l < 2; ++l) {
        // o_s = GAT_js(xj -> xs) + GAT_ss(xs -> xs)
        run_gat(xj, NJ, xs, NS, l * 3 + 0, js_src, js_dst, E_JS, offs_js, eid_js, esrc_js, os, 0);
        run_gat(xs, NS, xs, NS, l * 3 + 2, css, csd, E_SSL, offs_ss, eid_ss, esrc_ss, os, 1);
        // o_j = GAT_sj(xs -> xj)
        run_gat(xs, NS, xj, NJ, l * 3 + 1, sj_src, sj_dst, E_SJ, offs_sj, eid_sj, esrc_sj, oj, 0);
        // inter linears + relu (overwrite xj, xs)
        k_gemm<128, 2><<<cdiv(NJ, 64), 256, 0, stream>>>(
            oj, inter_W + (size_t)(l * 2 + 0) * 256 * 128, inter_b + (size_t)(l * 2 + 0) * 128,
            nullptr, nullptr, xj, NJ, 256);
        k_gemm<128, 2><<<cdiv(NS, 64), 256, 0, stream>>>(
            os, inter_W + (size_t)(l * 2 + 1) * 256 * 128, inter_b + (size_t)(l * 2 + 1) * 128,
            nullptr, nullptr, xs, NS, 256);
    }

    // final projections + scores
    k_gemm<128, 1><<<cdiv(NJ, 64), 256, 0, stream>>>(xj, Wjf, bjf, nullptr, nullptr, job_emb, NJ, 128);
    k_qvec<<<1, 128, 0, stream>>>(query, Wq, bq, qv);
    k_scores<<<cdiv(NJ, 4), 256, 0, stream>>>(job_emb, qv, scores, NJ);
}

// Round 2
// 1169.623 us; speedup vs baseline: 1.2795x; 1.2795x over previous
//
#include <hip/hip_runtime.h>
#include <hip/hip_bf16.h>
#include <math.h>

#define NJ 30000
#define NS 12000
#define E_JS 300000
#define E_SJ 300000
#define E_SS 150000
#define E_SSL (E_SS + NS)   // ss edges + self loops = 162000
#define SBERT 384
#define HIDDEN 128
#define OUTD 128

static inline int cdiv(int a, int b) { return (a + b - 1) / b; }

typedef __attribute__((ext_vector_type(8))) short bf8_t;
typedef __attribute__((ext_vector_type(4))) float f4_t;

__device__ inline float bf2f(unsigned short u) {
    union { unsigned int i; float f; } z; z.i = ((unsigned int)u) << 16; return z.f;
}
__device__ inline unsigned short f2bf(float f) {
    unsigned int x = __float_as_uint(f);
    unsigned int r = (x + 0x7fffu + ((x >> 16) & 1u)) >> 16;   // RNE
    return (unsigned short)r;
}

// ---------------------------------------------------------------------------
// Utility kernels
// ---------------------------------------------------------------------------
__global__ void k_fill_i32(int* __restrict__ p, int v, int n) {
    int i = blockIdx.x * 256 + threadIdx.x;
    if (i < n) p[i] = v;
}
__global__ void k_copy_i32(const int* __restrict__ a, int* __restrict__ b, int n) {
    int i = blockIdx.x * 256 + threadIdx.x;
    if (i < n) b[i] = a[i];
}
// first n2: -inf (softmax max), next n2: 0 (denominator)
__global__ void k_init_mden(float* __restrict__ p, int n2) {
    int i = blockIdx.x * 256 + threadIdx.x;
    if (i < n2) p[i] = -INFINITY;
    else if (i < 2 * n2) p[i] = 0.f;
}

__global__ void k_concat_ss(const int* __restrict__ s, const int* __restrict__ d,
                            int* __restrict__ cs, int* __restrict__ cd) {
    int i = blockIdx.x * 256 + threadIdx.x;
    if (i < E_SS) { cs[i] = s[i]; cd[i] = d[i]; }
    else if (i < E_SSL) { int n = i - E_SS; cs[i] = n; cd[i] = n; }
}

// ---------------------------------------------------------------------------
// cast fp32 x_job/x_skill -> bf16 (single launch, float4 -> ushort4)
// ---------------------------------------------------------------------------
__global__ void k_cast_x(const float* __restrict__ xj, const float* __restrict__ xs,
                         unsigned short* __restrict__ oj, unsigned short* __restrict__ os) {
    const int NJE = NJ * SBERT;
    const int TOT = (NJ + NS) * SBERT;
    int i4 = (blockIdx.x * 256 + threadIdx.x) * 4;
    if (i4 >= TOT) return;
    const float* src; unsigned short* dst; int off;
    if (i4 < NJE) { src = xj; dst = oj; off = i4; }
    else { src = xs; dst = os; off = i4 - NJE; }
    float4 v = *(const float4*)&src[off];
    ushort4 o; o.x = f2bf(v.x); o.y = f2bf(v.y); o.z = f2bf(v.z); o.w = f2bf(v.w);
    *(ushort4*)&dst[off] = o;
}

// ---------------------------------------------------------------------------
// batched weight transpose+cast: dst[n*K+k] = (bf16)src[k*N+n]
// ---------------------------------------------------------------------------
struct CastT { const float* src; unsigned short* dst; int K; int N; };
struct CastTList { CastT m[13]; };

__global__ void k_castT(CastTList L) {
    CastT c = L.m[blockIdx.y];
    int idx = blockIdx.x * 256 + threadIdx.x;
    int total = c.K * c.N;
    if (idx >= total) return;
    int n = idx / c.K, k = idx % c.K;
    c.dst[idx] = f2bf(c.src[(size_t)k * c.N + n]);
}

// ---------------------------------------------------------------------------
// Precompute ws_a / wd_a : wa[l,r][k][h] = sum_c W[l,r][k][h*128+c] * a[l,r][h][c]
// ---------------------------------------------------------------------------
__global__ void k_wa(const float* __restrict__ Ws, const float* __restrict__ as,
                     const float* __restrict__ Wd, const float* __restrict__ ad,
                     float* __restrict__ wsa, float* __restrict__ wda) {
    int id = blockIdx.x * 256 + threadIdx.x;   // 2 * 1536 total
    if (id >= 2 * 1536) return;
    int which = id / 1536;
    int r = id % 1536;
    int lr = r / 256;       // 0..5  (l*3 + rel)
    int kh = r % 256;
    int k = kh / 2, h = kh % 2;
    const float* W = which ? Wd : Ws;
    const float* a = which ? ad : as;
    const float* wrow = W + ((size_t)(lr * 128 + k)) * 256 + h * 128;
    const float* arow = a + (size_t)(lr * 2 + h) * 128;
    float acc = 0.f;
    for (int c = 0; c < 128; ++c) acc += wrow[c] * arow[c];
    (which ? wda : wsa)[lr * 256 + k * 2 + h] = acc;
}

// ---------------------------------------------------------------------------
// bf16 MFMA GEMM: Y[M, ldY](n0..n0+127) = X[M,K] @ Wt[n][k]^T
//   X bf16 [M,K], Wt bf16 [N][K] (pre-transposed). K % 32 == 0.
//   block = 256 thr (4 waves), tile BM=128 x BN=128, wave = 32m x 128n.
//   EPI: 0 none->bf16, 1 +bias->fp32, 2 +bias,relu->bf16, 3 +bias,LN,relu->bf16
//   n0 = blockIdx.y * 128
// ---------------------------------------------------------------------------
template <int EPI>
__global__ __launch_bounds__(256) void k_mgemm(
    const unsigned short* __restrict__ X, const unsigned short* __restrict__ Wt,
    const float* __restrict__ bias, const float* __restrict__ gamma,
    const float* __restrict__ beta, void* __restrict__ Yv, int M, int K, int ldY) {
    __shared__ __align__(16) unsigned short Al[128][40];
    __shared__ __align__(16) unsigned short Bl[128][40];
    const int t = threadIdx.x;
    const int wave = t >> 6, lane = t & 63;
    const int q = lane >> 4, c = lane & 15;
    const int row0 = blockIdx.x * 128;
    const int n0 = blockIdx.y * 128;

    f4_t acc[2][8];
#pragma unroll
    for (int mt = 0; mt < 2; ++mt)
#pragma unroll
        for (int nt = 0; nt < 8; ++nt) acc[mt][nt] = (f4_t){0.f, 0.f, 0.f, 0.f};

    for (int k0 = 0; k0 < K; k0 += 32) {
#pragma unroll
        for (int it = 0; it < 2; ++it) {
            int ch = t + it * 256;           // 0..511: 128 rows x 4 chunks(16B)
            int r = ch >> 2, cc = (ch & 3) * 8;
            int gr = row0 + r;
            uint4 va = (gr < M) ? *(const uint4*)&X[(size_t)gr * K + k0 + cc]
                                : make_uint4(0u, 0u, 0u, 0u);
            *(uint4*)&Al[r][cc] = va;
            uint4 vb = *(const uint4*)&Wt[(size_t)(n0 + r) * K + k0 + cc];
            *(uint4*)&Bl[r][cc] = vb;
        }
        __syncthreads();
        bf8_t af[2];
#pragma unroll
        for (int mt = 0; mt < 2; ++mt)
            af[mt] = *(const bf8_t*)&Al[wave * 32 + mt * 16 + c][q * 8];
#pragma unroll
        for (int nt = 0; nt < 8; ++nt) {
            bf8_t bfr = *(const bf8_t*)&Bl[nt * 16 + c][q * 8];
            acc[0][nt] = __builtin_amdgcn_mfma_f32_16x16x32_bf16(af[0], bfr, acc[0][nt], 0, 0, 0);
            acc[1][nt] = __builtin_amdgcn_mfma_f32_16x16x32_bf16(af[1], bfr, acc[1][nt], 0, 0, 0);
        }
        __syncthreads();
    }

    float bcol[8], gcol[8], becol[8];
#pragma unroll
    for (int nt = 0; nt < 8; ++nt) {
        bcol[nt] = (EPI >= 1) ? bias[n0 + nt * 16 + c] : 0.f;
        if constexpr (EPI == 3) {
            gcol[nt] = gamma[nt * 16 + c];
            becol[nt] = beta[nt * 16 + c];
        }
    }

#pragma unroll
    for (int mt = 0; mt < 2; ++mt) {
#pragma unroll
        for (int r = 0; r < 4; ++r) {
            int grow = row0 + wave * 32 + mt * 16 + q * 4 + r;
            float v[8];
#pragma unroll
            for (int nt = 0; nt < 8; ++nt) v[nt] = acc[mt][nt][r] + bcol[nt];
            if constexpr (EPI == 3) {
                float s = 0.f, ss = 0.f;
#pragma unroll
                for (int nt = 0; nt < 8; ++nt) { s += v[nt]; ss += v[nt] * v[nt]; }
#pragma unroll
                for (int m = 8; m >= 1; m >>= 1) {
                    s += __shfl_xor(s, m, 64);
                    ss += __shfl_xor(ss, m, 64);
                }
                float mu = s * (1.f / 128.f);
                float var = ss * (1.f / 128.f) - mu * mu;
                float rs = rsqrtf(var + 1e-5f);
#pragma unroll
                for (int nt = 0; nt < 8; ++nt)
                    v[nt] = fmaxf((v[nt] - mu) * rs * gcol[nt] + becol[nt], 0.f);
            } else if constexpr (EPI == 2) {
#pragma unroll
                for (int nt = 0; nt < 8; ++nt) v[nt] = fmaxf(v[nt], 0.f);
            }
            if (grow < M) {
                if constexpr (EPI == 1) {
                    float* Y = (float*)Yv;
#pragma unroll
                    for (int nt = 0; nt < 8; ++nt)
                        Y[(size_t)grow * ldY + n0 + nt * 16 + c] = v[nt];
                } else {
                    unsigned short* Y = (unsigned short*)Yv;
#pragma unroll
                    for (int nt = 0; nt < 8; ++nt)
                        Y[(size_t)grow * ldY + n0 + nt * 16 + c] = f2bf(v[nt]);
                }
            }
        }
    }
}

// ---------------------------------------------------------------------------
// alpha[n,h] = sum_k x[n,k] * wa[k*2+h]   (K = 128, wave per node, x bf16)
// ---------------------------------------------------------------------------
__global__ __launch_bounds__(256) void k_alpha(const unsigned short* __restrict__ x,
                                               const float* __restrict__ wa,
                                               float* __restrict__ out, int n) {
    int wave = threadIdx.x >> 6, lane = threadIdx.x & 63;
    int node = blockIdx.x * 4 + wave;
    if (node >= n) return;
    ushort2 xv = *(const ushort2*)&x[(size_t)node * 128 + lane * 2];
    float x0 = bf2f(xv.x), x1 = bf2f(xv.y);
    float4 wv = *(const float4*)&wa[lane * 4];  // (k0,h0) (k0,h1) (k1,h0) (k1,h1)
    float p0 = x0 * wv.x + x1 * wv.z;
    float p1 = x0 * wv.y + x1 * wv.w;
#pragma unroll
    for (int m = 32; m >= 1; m >>= 1) {
        p0 += __shfl_xor(p0, m, 64);
        p1 += __shfl_xor(p1, m, 64);
    }
    if (lane == 0) { out[node * 2] = p0; out[node * 2 + 1] = p1; }
}

// ---------------------------------------------------------------------------
// Edge softmax passes
// ---------------------------------------------------------------------------
__device__ inline void atomicMaxFloat(float* addr, float v) {
    if (v >= 0.f) atomicMax((int*)addr, __float_as_int(v));
    else atomicMin((unsigned int*)addr, __float_as_uint(v));
}

__global__ void k_edge_max(const int* __restrict__ src, const int* __restrict__ dst,
                           const float* __restrict__ as, const float* __restrict__ ad,
                           float* __restrict__ ee, float* __restrict__ m, int E) {
    int e = blockIdx.x * 256 + threadIdx.x;
    if (e >= E) return;
    int s = src[e], d = dst[e];
    float2 a = *(const float2*)&as[(size_t)s * 2];
    float2 b = *(const float2*)&ad[(size_t)d * 2];
    float v0 = a.x + b.x; v0 = v0 > 0.f ? v0 : 0.2f * v0;
    float v1 = a.y + b.y; v1 = v1 > 0.f ? v1 : 0.2f * v1;
    ee[(size_t)e * 2] = v0; ee[(size_t)e * 2 + 1] = v1;
    atomicMaxFloat(&m[(size_t)d * 2], v0);
    atomicMaxFloat(&m[(size_t)d * 2 + 1], v1);
}

__global__ void k_edge_expsum(const int* __restrict__ dst, float* __restrict__ ee,
                              const float* __restrict__ m, float* __restrict__ den, int E) {
    int e = blockIdx.x * 256 + threadIdx.x;
    if (e >= E) return;
    int d = dst[e];
    float2 mm = *(const float2*)&m[(size_t)d * 2];
    float p0 = expf(ee[(size_t)e * 2] - mm.x);
    float p1 = expf(ee[(size_t)e * 2 + 1] - mm.y);
    ee[(size_t)e * 2] = p0; ee[(size_t)e * 2 + 1] = p1;
    atomicAdd(&den[(size_t)d * 2], p0);
    atomicAdd(&den[(size_t)d * 2 + 1], p1);
}

// ---------------------------------------------------------------------------
// CSR build
// ---------------------------------------------------------------------------
__global__ void k_hist(const int* __restrict__ dst, int* __restrict__ deg, int E) {
    int e = blockIdx.x * 256 + threadIdx.x;
    if (e < E) atomicAdd(&deg[dst[e]], 1);
}

__global__ void k_exscan(const int* __restrict__ deg, int* __restrict__ offs, int n) {
    __shared__ int sdata[1024];
    __shared__ int carry;
    if (threadIdx.x == 0) carry = 0;
    __syncthreads();
    for (int base = 0; base < n; base += 1024) {
        int i = base + (int)threadIdx.x;
        int v = (i < n) ? deg[i] : 0;
        sdata[threadIdx.x] = v;
        __syncthreads();
        for (int off = 1; off < 1024; off <<= 1) {
            int tmp = (threadIdx.x >= (unsigned)off) ? sdata[threadIdx.x - off] : 0;
            __syncthreads();
            sdata[threadIdx.x] += tmp;
            __syncthreads();
        }
        if (i < n) offs[i] = carry + sdata[threadIdx.x] - v;
        __syncthreads();
        if (threadIdx.x == 1023) carry += sdata[1023];
        __syncthreads();
    }
    if (threadIdx.x == 0) offs[n] = carry;
}

__global__ void k_scatter(const int* __restrict__ src, const int* __restrict__ dst,
                          int* __restrict__ cur, int* __restrict__ eid,
                          int* __restrict__ esrc, int E) {
    int e = blockIdx.x * 256 + threadIdx.x;
    if (e >= E) return;
    int d = dst[e];
    int pos = atomicAdd(&cur[d], 1);
    eid[pos] = e;
    esrc[pos] = src[e];
}

// ---------------------------------------------------------------------------
// Gather: out[d,:256] (+)= (sum_e p[e,h]*hs[src_e,:])/(den[d,h]+eps) + bias
// hs bf16 [Nsrc,256]; out bf16. wave per dst node, lane covers 4 cols (8B).
// ---------------------------------------------------------------------------
__global__ __launch_bounds__(256) void k_gather(
    const int* __restrict__ offs, const int* __restrict__ eid, const int* __restrict__ esrc,
    const float* __restrict__ p, const unsigned short* __restrict__ hs,
    const float* __restrict__ den, const float* __restrict__ bias,
    unsigned short* __restrict__ out, int Nd, int accumulate) {
    int wave = threadIdx.x >> 6, lane = threadIdx.x & 63;
    int d = blockIdx.x * 4 + wave;
    if (d >= Nd) return;
    int c = lane * 4;
    bool h0 = c < 128;
    int beg = offs[d], end = offs[d + 1];
    float ax = 0.f, ay = 0.f, az = 0.f, aw = 0.f;
    for (int j = beg; j < end; ++j) {
        int e = eid[j];
        int s = esrc[j];
        float wgt = h0 ? p[(size_t)e * 2] : p[(size_t)e * 2 + 1];
        ushort4 hv = *(const ushort4*)&hs[(size_t)s * 256 + c];
        ax += wgt * bf2f(hv.x); ay += wgt * bf2f(hv.y);
        az += wgt * bf2f(hv.z); aw += wgt * bf2f(hv.w);
    }
    float dn = h0 ? den[(size_t)d * 2] : den[(size_t)d * 2 + 1];
    float sc = 1.f / (dn + 1e-16f);
    float4 b4 = *(const float4*)&bias[c];
    unsigned short* op = &out[(size_t)d * 256 + c];
    float o0 = ax * sc + b4.x, o1 = ay * sc + b4.y;
    float o2 = az * sc + b4.z, o3 = aw * sc + b4.w;
    if (accumulate) {
        ushort4 prev = *(ushort4*)op;
        o0 += bf2f(prev.x); o1 += bf2f(prev.y); o2 += bf2f(prev.z); o3 += bf2f(prev.w);
    }
    ushort4 o; o.x = f2bf(o0); o.y = f2bf(o1); o.z = f2bf(o2); o.w = f2bf(o3);
    *(ushort4*)op = o;
}

// ---------------------------------------------------------------------------
// q = query @ Wq + bq  (fp32)
// ---------------------------------------------------------------------------
__global__ void k_qvec(const float* __restrict__ query, const float* __restrict__ Wq,
                       const float* __restrict__ bq, float* __restrict__ qv) {
    int c = threadIdx.x;  // 128
    float acc = bq[c];
    for (int k = 0; k < SBERT; ++k) acc += query[k] * Wq[(size_t)k * 128 + c];
    qv[c] = acc;
}

// scores[r] = job_emb[r] . q   (wave per row, job_emb fp32)
__global__ __launch_bounds__(256) void k_scores(const float* __restrict__ jemb,
                                                const float* __restrict__ q,
                                                float* __restrict__ sc, int n) {
    int wave = threadIdx.x >> 6, lane = threadIdx.x & 63;
    int r = blockIdx.x * 4 + wave;
    if (r >= n) return;
    float2 a = *(const float2*)&jemb[(size_t)r * 128 + lane * 2];
    float2 b = *(const float2*)&q[lane * 2];
    float p = a.x * b.x + a.y * b.y;
#pragma unroll
    for (int m = 32; m >= 1; m >>= 1) p += __shfl_xor(p, m, 64);
    if (lane == 0) sc[r] = p;
}

// ---------------------------------------------------------------------------
extern "C" void kernel_launch(void* const* d_in, const int* in_sizes, int n_in,
                              void* d_out, int out_size, void* d_ws, size_t ws_size,
                              hipStream_t stream) {
    const float* x_job   = (const float*)d_in[0];
    const float* x_skill = (const float*)d_in[1];
    const int* js_src = (const int*)d_in[2];
    const int* js_dst = (const int*)d_in[3];
    const int* sj_src = (const int*)d_in[4];
    const int* sj_dst = (const int*)d_in[5];
    const int* ss_src = (const int*)d_in[6];
    const int* ss_dst = (const int*)d_in[7];
    const float* query    = (const float*)d_in[8];
    const float* W0_job   = (const float*)d_in[9];
    const float* b0_job   = (const float*)d_in[10];
    const float* g0_job   = (const float*)d_in[11];
    const float* be0_job  = (const float*)d_in[12];
    const float* W0_skill = (const float*)d_in[13];
    const float* b0_skill = (const float*)d_in[14];
    const float* g0_skill = (const float*)d_in[15];
    const float* be0_skill= (const float*)d_in[16];
    const float* gat_Ws = (const float*)d_in[17];
    const float* gat_Wd = (const float*)d_in[18];
    const float* gat_as = (const float*)d_in[19];
    const float* gat_ad = (const float*)d_in[20];
    const float* gat_b  = (const float*)d_in[21];
    const float* inter_W = (const float*)d_in[22];
    const float* inter_b = (const float*)d_in[23];
    const float* Wjf = (const float*)d_in[24];
    const float* bjf = (const float*)d_in[25];
    const float* Wq  = (const float*)d_in[26];
    const float* bq  = (const float*)d_in[27];

    // workspace carve (256B aligned bump allocator)
    char* w = (char*)d_ws;
    auto alloc = [&](size_t bytes) -> void* {
        void* p = (void*)w;
        w += (bytes + 255) & ~(size_t)255;
        return p;
    };
    typedef unsigned short u16;
    u16* xjob_b   = (u16*)alloc((size_t)NJ * SBERT * 2);
    u16* xskill_b = (u16*)alloc((size_t)NS * SBERT * 2);
    u16* xj  = (u16*)alloc((size_t)NJ * 128 * 2);
    u16* xs  = (u16*)alloc((size_t)NS * 128 * 2);
    u16* hs  = (u16*)alloc((size_t)NJ * 256 * 2);
    u16* oj  = (u16*)alloc((size_t)NJ * 256 * 2);
    u16* os  = (u16*)alloc((size_t)NS * 256 * 2);
    // transposed bf16 weights
    u16* WtW0j = (u16*)alloc((size_t)SBERT * 128 * 2);
    u16* WtW0s = (u16*)alloc((size_t)SBERT * 128 * 2);
    u16* WtWs  = (u16*)alloc((size_t)6 * 128 * 256 * 2);   // [lr][256][128]
    u16* WtI   = (u16*)alloc((size_t)4 * 256 * 128 * 2);   // [i][128][256]
    u16* WtJf  = (u16*)alloc((size_t)128 * 128 * 2);
    float* pbuf = (float*)alloc((size_t)E_JS * 2 * 4);
    float* asb = (float*)alloc((size_t)NJ * 2 * 4);
    float* adb = (float*)alloc((size_t)NJ * 2 * 4);
    float* mden = (float*)alloc((size_t)NJ * 4 * 4);   // [m | den]
    float* mbuf = mden;
    float* wsa = (float*)alloc(6 * 256 * 4);
    float* wda = (float*)alloc(6 * 256 * 4);
    int* css = (int*)alloc((size_t)E_SSL * 4);
    int* csd = (int*)alloc((size_t)E_SSL * 4);
    int* offs_js = (int*)alloc((NS + 1) * 4);
    int* eid_js  = (int*)alloc((size_t)E_JS * 4);
    int* esrc_js = (int*)alloc((size_t)E_JS * 4);
    int* offs_sj = (int*)alloc((NJ + 1) * 4);
    int* eid_sj  = (int*)alloc((size_t)E_SJ * 4);
    int* esrc_sj = (int*)alloc((size_t)E_SJ * 4);
    int* offs_ss = (int*)alloc((NS + 1) * 4);
    int* eid_ss  = (int*)alloc((size_t)E_SSL * 4);
    int* esrc_ss = (int*)alloc((size_t)E_SSL * 4);
    int* deg = (int*)alloc((size_t)NJ * 4);
    int* cur = (int*)alloc((size_t)NJ * 4);

    float* out = (float*)d_out;
    float* scores  = out;
    float* job_emb = out + NJ;
    float* qv      = out + NJ + (size_t)NJ * 128;

    // --- casts: x -> bf16, weights -> transposed bf16 ---
    {
        int tot4 = (NJ + NS) * SBERT / 4;
        k_cast_x<<<cdiv(tot4, 256), 256, 0, stream>>>(x_job, x_skill, xjob_b, xskill_b);
        CastTList L;
        L.m[0] = {W0_job, WtW0j, SBERT, 128};
        L.m[1] = {W0_skill, WtW0s, SBERT, 128};
        for (int lr = 0; lr < 6; ++lr)
            L.m[2 + lr] = {gat_Ws + (size_t)lr * 128 * 256, WtWs + (size_t)lr * 256 * 128, 128, 256};
        for (int i = 0; i < 4; ++i)
            L.m[8 + i] = {inter_W + (size_t)i * 256 * 128, WtI + (size_t)i * 128 * 256, 256, 128};
        L.m[12] = {Wjf, WtJf, 128, 128};
        k_castT<<<dim3(cdiv(SBERT * 128, 256), 13), 256, 0, stream>>>(L);
    }

    // --- precompute attention weight vectors ---
    k_wa<<<cdiv(2 * 1536, 256), 256, 0, stream>>>(gat_Ws, gat_as, gat_Wd, gat_ad, wsa, wda);

    // --- initial linear + LN + relu (bf16 MFMA) ---
    k_mgemm<3><<<dim3(cdiv(NJ, 128), 1), 256, 0, stream>>>(
        xjob_b, WtW0j, b0_job, g0_job, be0_job, xj, NJ, SBERT, 128);
    k_mgemm<3><<<dim3(cdiv(NS, 128), 1), 256, 0, stream>>>(
        xskill_b, WtW0s, b0_skill, g0_skill, be0_skill, xs, NS, SBERT, 128);

    // --- ss edges with self loops ---
    k_concat_ss<<<cdiv(E_SSL, 256), 256, 0, stream>>>(ss_src, ss_dst, css, csd);

    // --- CSR builds (layer-invariant) ---
    auto build_csr = [&](const int* srcA, const int* dstA, int E, int Nd,
                         int* offs, int* eid, int* esrc) {
        k_fill_i32<<<cdiv(Nd, 256), 256, 0, stream>>>(deg, 0, Nd);
        k_hist<<<cdiv(E, 256), 256, 0, stream>>>(dstA, deg, E);
        k_exscan<<<1, 1024, 0, stream>>>(deg, offs, Nd);
        k_copy_i32<<<cdiv(Nd, 256), 256, 0, stream>>>(offs, cur, Nd);
        k_scatter<<<cdiv(E, 256), 256, 0, stream>>>(srcA, dstA, cur, eid, esrc, E);
    };
    build_csr(js_src, js_dst, E_JS, NS, offs_js, eid_js, esrc_js);
    build_csr(sj_src, sj_dst, E_SJ, NJ, offs_sj, eid_sj, esrc_sj);
    build_csr(css, csd, E_SSL, NS, offs_ss, eid_ss, esrc_ss);

    auto run_gat = [&](const u16* x_src, int Nsrc, const u16* x_dst, int Nd, int lr,
                       const int* srcA, const int* dstA, int E,
                       const int* offs, const int* eid, const int* esrc,
                       u16* outbuf, int accumulate) {
        float* den = mden + (size_t)Nd * 2;
        k_mgemm<0><<<dim3(cdiv(Nsrc, 128), 2), 256, 0, stream>>>(
            x_src, WtWs + (size_t)lr * 256 * 128, nullptr, nullptr, nullptr, hs, Nsrc, 128, 256);
        k_alpha<<<cdiv(Nsrc, 4), 256, 0, stream>>>(x_src, wsa + lr * 256, asb, Nsrc);
        k_alpha<<<cdiv(Nd, 4), 256, 0, stream>>>(x_dst, wda + lr * 256, adb, Nd);
        k_init_mden<<<cdiv(Nd * 4, 256), 256, 0, stream>>>(mden, Nd * 2);
        k_edge_max<<<cdiv(E, 256), 256, 0, stream>>>(srcA, dstA, asb, adb, pbuf, mbuf, E);
        k_edge_expsum<<<cdiv(E, 256), 256, 0, stream>>>(dstA, pbuf, mbuf, den, E);
        k_gather<<<cdiv(Nd, 4), 256, 0, stream>>>(offs, eid, esrc, pbuf, hs, den,
                                                  gat_b + (size_t)lr * 256, outbuf, Nd, accumulate);
    };

    for (int l = 0; l < 2; ++l) {
        // o_s = GAT_js(xj -> xs) + GAT_ss(xs -> xs)
        run_gat(xj, NJ, xs, NS, l * 3 + 0, js_src, js_dst, E_JS, offs_js, eid_js, esrc_js, os, 0);
        run_gat(xs, NS, xs, NS, l * 3 + 2, css, csd, E_SSL, offs_ss, eid_ss, esrc_ss, os, 1);
        // o_j = GAT_sj(xs -> xj)
        run_gat(xs, NS, xj, NJ, l * 3 + 1, sj_src, sj_dst, E_SJ, offs_sj, eid_sj, esrc_sj, oj, 0);
        // inter linears + relu (overwrite xj, xs)
        k_mgemm<2><<<dim3(cdiv(NJ, 128), 1), 256, 0, stream>>>(
            oj, WtI + (size_t)(l * 2 + 0) * 128 * 256, inter_b + (size_t)(l * 2 + 0) * 128,
            nullptr, nullptr, xj, NJ, 256, 128);
        k_mgemm<2><<<dim3(cdiv(NS, 128), 1), 256, 0, stream>>>(
            os, WtI + (size_t)(l * 2 + 1) * 128 * 256, inter_b + (size_t)(l * 2 + 1) * 128,
            nullptr, nullptr, xs, NS, 256, 128);
    }

    // final projections + scores
    k_mgemm<1><<<dim3(cdiv(NJ, 128), 1), 256, 0, stream>>>(
        xj, WtJf, bjf, nullptr, nullptr, job_emb, NJ, 128, 128);
    k_qvec<<<1, 128, 0, stream>>>(query, Wq, bq, qv);
    k_scores<<<cdiv(NJ, 4), 256, 0, stream>>>(job_emb, qv, scores, NJ);
}

// Round 3
// 676.287 us; speedup vs baseline: 2.2129x; 1.7295x over previous
//
#include <hip/hip_runtime.h>
#include <hip/hip_bf16.h>
#include <math.h>

#define NJ 30000
#define NS 12000
#define E_JS 300000
#define E_SJ 300000
#define E_SS 150000
#define ETOT (E_JS + E_SJ + E_SS + NS)   // 762000 incl. ss self loops
#define NBINS (NS + NJ + NS)             // 54000 combined dst bins
#define SBERT 384
#define HIDDEN 128
#define OUTD 128
#define SCAN_B 1024
#define SCAN_NB ((NBINS + SCAN_B - 1) / SCAN_B)   // 53

static inline int cdiv(int a, int b) { return (a + b - 1) / b; }

typedef __attribute__((ext_vector_type(8))) short bf8_t;
typedef __attribute__((ext_vector_type(4))) float f4_t;

__device__ inline float bf2f(unsigned short u) {
    union { unsigned int i; float f; } z; z.i = ((unsigned int)u) << 16; return z.f;
}
__device__ inline unsigned short f2bf(float f) {
    unsigned int x = __float_as_uint(f);
    unsigned int r = (x + 0x7fffu + ((x >> 16) & 1u)) >> 16;   // RNE
    return (unsigned short)r;
}

// ---------------------------------------------------------------------------
// Utility kernels
// ---------------------------------------------------------------------------
__global__ void k_fill_i32(int* __restrict__ p, int v, int n) {
    int i = blockIdx.x * 256 + threadIdx.x;
    if (i < n) p[i] = v;
}
__global__ void k_copy_i32(const int* __restrict__ a, int* __restrict__ b, int n) {
    int i = blockIdx.x * 256 + threadIdx.x;
    if (i < n) b[i] = a[i];
}

// ---------------------------------------------------------------------------
// cast fp32 x_job/x_skill -> bf16
// ---------------------------------------------------------------------------
__global__ void k_cast_x(const float* __restrict__ xj, const float* __restrict__ xs,
                         unsigned short* __restrict__ oj, unsigned short* __restrict__ os) {
    const int NJE = NJ * SBERT;
    const int TOT = (NJ + NS) * SBERT;
    int i4 = (blockIdx.x * 256 + threadIdx.x) * 4;
    if (i4 >= TOT) return;
    const float* src; unsigned short* dst; int off;
    if (i4 < NJE) { src = xj; dst = oj; off = i4; }
    else { src = xs; dst = os; off = i4 - NJE; }
    float4 v = *(const float4*)&src[off];
    ushort4 o; o.x = f2bf(v.x); o.y = f2bf(v.y); o.z = f2bf(v.z); o.w = f2bf(v.w);
    *(ushort4*)&dst[off] = o;
}

// ---------------------------------------------------------------------------
// batched weight transpose+cast: dst[n*K+k] = (bf16)src[k*N+n]
// ---------------------------------------------------------------------------
struct CastT { const float* src; unsigned short* dst; int K; int N; };
struct CastTList { CastT m[13]; };

__global__ void k_castT(CastTList L) {
    CastT c = L.m[blockIdx.y];
    int idx = blockIdx.x * 256 + threadIdx.x;
    int total = c.K * c.N;
    if (idx >= total) return;
    int n = idx / c.K, k = idx % c.K;
    c.dst[idx] = f2bf(c.src[(size_t)k * c.N + n]);
}

// ---------------------------------------------------------------------------
// Precompute ws_a / wd_a : wa[l,r][k][h] = sum_c W[l,r][k][h*128+c] * a[l,r][h][c]
// ---------------------------------------------------------------------------
__global__ void k_wa(const float* __restrict__ Ws, const float* __restrict__ as,
                     const float* __restrict__ Wd, const float* __restrict__ ad,
                     float* __restrict__ wsa, float* __restrict__ wda) {
    int id = blockIdx.x * 256 + threadIdx.x;   // 2 * 1536 total
    if (id >= 2 * 1536) return;
    int which = id / 1536;
    int r = id % 1536;
    int lr = r / 256;       // 0..5  (l*3 + rel)
    int kh = r % 256;
    int k = kh / 2, h = kh % 2;
    const float* W = which ? Wd : Ws;
    const float* a = which ? ad : as;
    const float* wrow = W + ((size_t)(lr * 128 + k)) * 256 + h * 128;
    const float* arow = a + (size_t)(lr * 2 + h) * 128;
    float acc = 0.f;
    for (int c = 0; c < 128; ++c) acc += wrow[c] * arow[c];
    (which ? wda : wsa)[lr * 256 + k * 2 + h] = acc;
}

// ---------------------------------------------------------------------------
// bf16 MFMA GEMM (same as round 2): Y[M,ldY](n0..n0+127) = X[M,K] @ Wt[n][k]^T
// ---------------------------------------------------------------------------
template <int EPI>
__global__ __launch_bounds__(256) void k_mgemm(
    const unsigned short* __restrict__ X, const unsigned short* __restrict__ Wt,
    const float* __restrict__ bias, const float* __restrict__ gamma,
    const float* __restrict__ beta, void* __restrict__ Yv, int M, int K, int ldY) {
    __shared__ __align__(16) unsigned short Al[128][40];
    __shared__ __align__(16) unsigned short Bl[128][40];
    const int t = threadIdx.x;
    const int wave = t >> 6, lane = t & 63;
    const int q = lane >> 4, c = lane & 15;
    const int row0 = blockIdx.x * 128;
    const int n0 = blockIdx.y * 128;

    f4_t acc[2][8];
#pragma unroll
    for (int mt = 0; mt < 2; ++mt)
#pragma unroll
        for (int nt = 0; nt < 8; ++nt) acc[mt][nt] = (f4_t){0.f, 0.f, 0.f, 0.f};

    for (int k0 = 0; k0 < K; k0 += 32) {
#pragma unroll
        for (int it = 0; it < 2; ++it) {
            int ch = t + it * 256;           // 0..511: 128 rows x 4 chunks(16B)
            int r = ch >> 2, cc = (ch & 3) * 8;
            int gr = row0 + r;
            uint4 va = (gr < M) ? *(const uint4*)&X[(size_t)gr * K + k0 + cc]
                                : make_uint4(0u, 0u, 0u, 0u);
            *(uint4*)&Al[r][cc] = va;
            uint4 vb = *(const uint4*)&Wt[(size_t)(n0 + r) * K + k0 + cc];
            *(uint4*)&Bl[r][cc] = vb;
        }
        __syncthreads();
        bf8_t af[2];
#pragma unroll
        for (int mt = 0; mt < 2; ++mt)
            af[mt] = *(const bf8_t*)&Al[wave * 32 + mt * 16 + c][q * 8];
#pragma unroll
        for (int nt = 0; nt < 8; ++nt) {
            bf8_t bfr = *(const bf8_t*)&Bl[nt * 16 + c][q * 8];
            acc[0][nt] = __builtin_amdgcn_mfma_f32_16x16x32_bf16(af[0], bfr, acc[0][nt], 0, 0, 0);
            acc[1][nt] = __builtin_amdgcn_mfma_f32_16x16x32_bf16(af[1], bfr, acc[1][nt], 0, 0, 0);
        }
        __syncthreads();
    }

    float bcol[8], gcol[8], becol[8];
#pragma unroll
    for (int nt = 0; nt < 8; ++nt) {
        bcol[nt] = (EPI >= 1) ? bias[n0 + nt * 16 + c] : 0.f;
        if constexpr (EPI == 3) {
            gcol[nt] = gamma[nt * 16 + c];
            becol[nt] = beta[nt * 16 + c];
        }
    }

#pragma unroll
    for (int mt = 0; mt < 2; ++mt) {
#pragma unroll
        for (int r = 0; r < 4; ++r) {
            int grow = row0 + wave * 32 + mt * 16 + q * 4 + r;
            float v[8];
#pragma unroll
            for (int nt = 0; nt < 8; ++nt) v[nt] = acc[mt][nt][r] + bcol[nt];
            if constexpr (EPI == 3) {
                float s = 0.f, ss = 0.f;
#pragma unroll
                for (int nt = 0; nt < 8; ++nt) { s += v[nt]; ss += v[nt] * v[nt]; }
#pragma unroll
                for (int m = 8; m >= 1; m >>= 1) {
                    s += __shfl_xor(s, m, 64);
                    ss += __shfl_xor(ss, m, 64);
                }
                float mu = s * (1.f / 128.f);
                float var = ss * (1.f / 128.f) - mu * mu;
                float rs = rsqrtf(var + 1e-5f);
#pragma unroll
                for (int nt = 0; nt < 8; ++nt)
                    v[nt] = fmaxf((v[nt] - mu) * rs * gcol[nt] + becol[nt], 0.f);
            } else if constexpr (EPI == 2) {
#pragma unroll
                for (int nt = 0; nt < 8; ++nt) v[nt] = fmaxf(v[nt], 0.f);
            }
            if (grow < M) {
                if constexpr (EPI == 1) {
                    float* Y = (float*)Yv;
#pragma unroll
                    for (int nt = 0; nt < 8; ++nt)
                        Y[(size_t)grow * ldY + n0 + nt * 16 + c] = v[nt];
                } else {
                    unsigned short* Y = (unsigned short*)Yv;
#pragma unroll
                    for (int nt = 0; nt < 8; ++nt)
                        Y[(size_t)grow * ldY + n0 + nt * 16 + c] = f2bf(v[nt]);
                }
            }
        }
    }
}

// ---------------------------------------------------------------------------
// Per-layer alpha precompute: for each node, all needed (rel,role) dot products.
//   job node n  -> aJ[n][4] = {as_js(h0,h1), ad_sj(h0,h1)}
//   skill node n-> aS[n][8] = {as_ss(h0,h1), ad_js(h0,h1), as_sj(h0,h1), ad_ss(h0,h1)}
// wa layout per (l,r): [k*2+h], lane covers k=lane*2, lane*2+1.
// ---------------------------------------------------------------------------
__global__ __launch_bounds__(256) void k_alpha_all(
    const unsigned short* __restrict__ xj, const unsigned short* __restrict__ xs,
    const float* __restrict__ wsa, const float* __restrict__ wda, int l3,
    float* __restrict__ aJ, float* __restrict__ aS) {
    int wave = threadIdx.x >> 6, lane = threadIdx.x & 63;
    int node = blockIdx.x * 4 + wave;
    if (node < NJ) {
        ushort2 xv = *(const ushort2*)&xj[(size_t)node * 128 + lane * 2];
        float x0 = bf2f(xv.x), x1 = bf2f(xv.y);
        float4 w0 = *(const float4*)&wsa[(size_t)(l3 + 0) * 256 + lane * 4];
        float4 w1 = *(const float4*)&wda[(size_t)(l3 + 1) * 256 + lane * 4];
        float p0 = x0 * w0.x + x1 * w0.z, p1 = x0 * w0.y + x1 * w0.w;
        float p2 = x0 * w1.x + x1 * w1.z, p3 = x0 * w1.y + x1 * w1.w;
#pragma unroll
        for (int m = 32; m >= 1; m >>= 1) {
            p0 += __shfl_xor(p0, m, 64); p1 += __shfl_xor(p1, m, 64);
            p2 += __shfl_xor(p2, m, 64); p3 += __shfl_xor(p3, m, 64);
        }
        if (lane == 0) {
            float4* o = (float4*)&aJ[(size_t)node * 4];
            *o = make_float4(p0, p1, p2, p3);
        }
    } else if (node < NJ + NS) {
        int n = node - NJ;
        ushort2 xv = *(const ushort2*)&xs[(size_t)n * 128 + lane * 2];
        float x0 = bf2f(xv.x), x1 = bf2f(xv.y);
        float4 wA = *(const float4*)&wsa[(size_t)(l3 + 2) * 256 + lane * 4];  // as ss
        float4 wB = *(const float4*)&wda[(size_t)(l3 + 0) * 256 + lane * 4];  // ad js
        float4 wC = *(const float4*)&wsa[(size_t)(l3 + 1) * 256 + lane * 4];  // as sj
        float4 wD = *(const float4*)&wda[(size_t)(l3 + 2) * 256 + lane * 4];  // ad ss
        float p0 = x0 * wA.x + x1 * wA.z, p1 = x0 * wA.y + x1 * wA.w;
        float p2 = x0 * wB.x + x1 * wB.z, p3 = x0 * wB.y + x1 * wB.w;
        float p4 = x0 * wC.x + x1 * wC.z, p5 = x0 * wC.y + x1 * wC.w;
        float p6 = x0 * wD.x + x1 * wD.z, p7 = x0 * wD.y + x1 * wD.w;
#pragma unroll
        for (int m = 32; m >= 1; m >>= 1) {
            p0 += __shfl_xor(p0, m, 64); p1 += __shfl_xor(p1, m, 64);
            p2 += __shfl_xor(p2, m, 64); p3 += __shfl_xor(p3, m, 64);
            p4 += __shfl_xor(p4, m, 64); p5 += __shfl_xor(p5, m, 64);
            p6 += __shfl_xor(p6, m, 64); p7 += __shfl_xor(p7, m, 64);
        }
        if (lane == 0) {
            float4* o = (float4*)&aS[(size_t)n * 8];
            o[0] = make_float4(p0, p1, p2, p3);
            o[1] = make_float4(p4, p5, p6, p7);
        }
    }
}

// ---------------------------------------------------------------------------
// Combined CSR over all relations. Bin layout:
//   [0,NS)            js dst (skill)
//   [NS,NS+NJ)        sj dst (job)
//   [NS+NJ,NS+NJ+NS)  ss dst (skill) incl. self loops
// ---------------------------------------------------------------------------
__device__ inline void edge_decode(int e, const int* js_src, const int* js_dst,
                                   const int* sj_src, const int* sj_dst,
                                   const int* ss_src, const int* ss_dst,
                                   int& src, int& bin) {
    if (e < E_JS) { src = js_src[e]; bin = js_dst[e]; }
    else if (e < E_JS + E_SJ) { int i = e - E_JS; src = sj_src[i]; bin = NS + sj_dst[i]; }
    else if (e < E_JS + E_SJ + E_SS) { int i = e - E_JS - E_SJ; src = ss_src[i]; bin = NS + NJ + ss_dst[i]; }
    else { int i = e - E_JS - E_SJ - E_SS; src = i; bin = NS + NJ + i; }
}

__global__ void k_hist_all(const int* __restrict__ js_src, const int* __restrict__ js_dst,
                           const int* __restrict__ sj_src, const int* __restrict__ sj_dst,
                           const int* __restrict__ ss_src, const int* __restrict__ ss_dst,
                           int* __restrict__ deg) {
    int e = blockIdx.x * 256 + threadIdx.x;
    if (e >= ETOT) return;
    int src, bin;
    edge_decode(e, js_src, js_dst, sj_src, sj_dst, ss_src, ss_dst, src, bin);
    atomicAdd(&deg[bin], 1);
}

__global__ void k_scatter_all(const int* __restrict__ js_src, const int* __restrict__ js_dst,
                              const int* __restrict__ sj_src, const int* __restrict__ sj_dst,
                              const int* __restrict__ ss_src, const int* __restrict__ ss_dst,
                              int* __restrict__ cur, int* __restrict__ esrc) {
    int e = blockIdx.x * 256 + threadIdx.x;
    if (e >= ETOT) return;
    int src, bin;
    edge_decode(e, js_src, js_dst, sj_src, sj_dst, ss_src, ss_dst, src, bin);
    int pos = atomicAdd(&cur[bin], 1);
    esrc[pos] = src;
}

// multi-block exclusive scan: scan1 (block-local excl + block sums),
// scan2 (single-wave scan of block sums), scan3 (add prev-block totals)
__global__ void k_scan1(const int* __restrict__ deg, int* __restrict__ offs,
                        int* __restrict__ bsum, int n) {
    __shared__ int sd[SCAN_B];
    int b = blockIdx.x;
    int i = b * SCAN_B + threadIdx.x;
    int v = (i < n) ? deg[i] : 0;
    sd[threadIdx.x] = v;
    __syncthreads();
    for (int off = 1; off < SCAN_B; off <<= 1) {
        int t = (threadIdx.x >= (unsigned)off) ? sd[threadIdx.x - off] : 0;
        __syncthreads();
        sd[threadIdx.x] += t;
        __syncthreads();
    }
    if (i < n) offs[i] = sd[threadIdx.x] - v;   // block-local exclusive
    if (threadIdx.x == SCAN_B - 1) bsum[b] = sd[SCAN_B - 1];
}

__global__ void k_scan2(int* __restrict__ bsum, int nb) {
    int lane = threadIdx.x;   // 64 threads
    int v = (lane < nb) ? bsum[lane] : 0;
#pragma unroll
    for (int off = 1; off < 64; off <<= 1) {
        int t = __shfl_up(v, off, 64);
        if (lane >= off) v += t;
    }
    if (lane < nb) bsum[lane] = v;   // inclusive
}

__global__ void k_scan3(int* __restrict__ offs, const int* __restrict__ bsum, int n, int nb) {
    int b = blockIdx.x;
    int i = b * SCAN_B + threadIdx.x;
    int add = (b > 0) ? bsum[b - 1] : 0;
    if (i < n) offs[i] += add;
    if (i == 0) offs[n] = bsum[nb - 1];
}

// ---------------------------------------------------------------------------
// Fused gather + edge softmax (no max-subtraction; e is LN-bounded small):
// out[d,:256] (+)= (sum_e exp(leaky(aS[s]+aD[d])) * hs[s,:]) / den + bias
// wave per dst node; lane covers 4 cols of its head; per-lane den.
// ---------------------------------------------------------------------------
__global__ __launch_bounds__(256) void k_gather(
    const int* __restrict__ offs, const int* __restrict__ esrc,
    const float* __restrict__ aS, int sStride,
    const float* __restrict__ aD, int dStride,
    const unsigned short* __restrict__ hs, const float* __restrict__ bias,
    unsigned short* __restrict__ out, int Nd, int accumulate) {
    int wave = threadIdx.x >> 6, lane = threadIdx.x & 63;
    int d = blockIdx.x * 4 + wave;
    if (d >= Nd) return;
    int c = lane * 4;
    int h = (c >= 128) ? 1 : 0;
    float ad = aD[(size_t)d * dStride + h];
    int beg = offs[d], end = offs[d + 1];
    float ax = 0.f, ay = 0.f, az = 0.f, aw = 0.f, den = 0.f;
    for (int j = beg; j < end; ++j) {
        int s = esrc[j];
        float as = aS[(size_t)s * sStride + h];
        float e = as + ad;
        e = e > 0.f ? e : 0.2f * e;
        float p = __expf(e);
        ushort4 hv = *(const ushort4*)&hs[(size_t)s * 256 + c];
        ax += p * bf2f(hv.x); ay += p * bf2f(hv.y);
        az += p * bf2f(hv.z); aw += p * bf2f(hv.w);
        den += p;
    }
    float sc = 1.f / (den + 1e-16f);
    float4 b4 = *(const float4*)&bias[c];
    unsigned short* op = &out[(size_t)d * 256 + c];
    float o0 = ax * sc + b4.x, o1 = ay * sc + b4.y;
    float o2 = az * sc + b4.z, o3 = aw * sc + b4.w;
    if (accumulate) {
        ushort4 prev = *(ushort4*)op;
        o0 += bf2f(prev.x); o1 += bf2f(prev.y); o2 += bf2f(prev.z); o3 += bf2f(prev.w);
    }
    ushort4 o; o.x = f2bf(o0); o.y = f2bf(o1); o.z = f2bf(o2); o.w = f2bf(o3);
    *(ushort4*)op = o;
}

// ---------------------------------------------------------------------------
// q = query @ Wq + bq  (fp32)
// ---------------------------------------------------------------------------
__global__ void k_qvec(const float* __restrict__ query, const float* __restrict__ Wq,
                       const float* __restrict__ bq, float* __restrict__ qv) {
    int c = threadIdx.x;  // 128
    float acc = bq[c];
    for (int k = 0; k < SBERT; ++k) acc += query[k] * Wq[(size_t)k * 128 + c];
    qv[c] = acc;
}

// scores[r] = job_emb[r] . q   (wave per row, job_emb fp32)
__global__ __launch_bounds__(256) void k_scores(const float* __restrict__ jemb,
                                                const float* __restrict__ q,
                                                float* __restrict__ sc, int n) {
    int wave = threadIdx.x >> 6, lane = threadIdx.x & 63;
    int r = blockIdx.x * 4 + wave;
    if (r >= n) return;
    float2 a = *(const float2*)&jemb[(size_t)r * 128 + lane * 2];
    float2 b = *(const float2*)&q[lane * 2];
    float p = a.x * b.x + a.y * b.y;
#pragma unroll
    for (int m = 32; m >= 1; m >>= 1) p += __shfl_xor(p, m, 64);
    if (lane == 0) sc[r] = p;
}

// ---------------------------------------------------------------------------
extern "C" void kernel_launch(void* const* d_in, const int* in_sizes, int n_in,
                              void* d_out, int out_size, void* d_ws, size_t ws_size,
                              hipStream_t stream) {
    const float* x_job   = (const float*)d_in[0];
    const float* x_skill = (const float*)d_in[1];
    const int* js_src = (const int*)d_in[2];
    const int* js_dst = (const int*)d_in[3];
    const int* sj_src = (const int*)d_in[4];
    const int* sj_dst = (const int*)d_in[5];
    const int* ss_src = (const int*)d_in[6];
    const int* ss_dst = (const int*)d_in[7];
    const float* query    = (const float*)d_in[8];
    const float* W0_job   = (const float*)d_in[9];
    const float* b0_job   = (const float*)d_in[10];
    const float* g0_job   = (const float*)d_in[11];
    const float* be0_job  = (const float*)d_in[12];
    const float* W0_skill = (const float*)d_in[13];
    const float* b0_skill = (const float*)d_in[14];
    const float* g0_skill = (const float*)d_in[15];
    const float* be0_skill= (const float*)d_in[16];
    const float* gat_Ws = (const float*)d_in[17];
    const float* gat_Wd = (const float*)d_in[18];
    const float* gat_as = (const float*)d_in[19];
    const float* gat_ad = (const float*)d_in[20];
    const float* gat_b  = (const float*)d_in[21];
    const float* inter_W = (const float*)d_in[22];
    const float* inter_b = (const float*)d_in[23];
    const float* Wjf = (const float*)d_in[24];
    const float* bjf = (const float*)d_in[25];
    const float* Wq  = (const float*)d_in[26];
    const float* bq  = (const float*)d_in[27];

    // workspace carve (256B aligned bump allocator)
    char* w = (char*)d_ws;
    auto alloc = [&](size_t bytes) -> void* {
        void* p = (void*)w;
        w += (bytes + 255) & ~(size_t)255;
        return p;
    };
    typedef unsigned short u16;
    u16* xjob_b   = (u16*)alloc((size_t)NJ * SBERT * 2);
    u16* xskill_b = (u16*)alloc((size_t)NS * SBERT * 2);
    u16* xj  = (u16*)alloc((size_t)NJ * 128 * 2);
    u16* xs  = (u16*)alloc((size_t)NS * 128 * 2);
    u16* hs  = (u16*)alloc((size_t)NJ * 256 * 2);
    u16* oj  = (u16*)alloc((size_t)NJ * 256 * 2);
    u16* os  = (u16*)alloc((size_t)NS * 256 * 2);
    // transposed bf16 weights
    u16* WtW0j = (u16*)alloc((size_t)SBERT * 128 * 2);
    u16* WtW0s = (u16*)alloc((size_t)SBERT * 128 * 2);
    u16* WtWs  = (u16*)alloc((size_t)6 * 128 * 256 * 2);   // [lr][256][128]
    u16* WtI   = (u16*)alloc((size_t)4 * 256 * 128 * 2);   // [i][128][256]
    u16* WtJf  = (u16*)alloc((size_t)128 * 128 * 2);
    float* aJ = (float*)alloc((size_t)NJ * 4 * 4);
    float* aS = (float*)alloc((size_t)NS * 8 * 4);
    float* wsa = (float*)alloc(6 * 256 * 4);
    float* wda = (float*)alloc(6 * 256 * 4);
    int* deg  = (int*)alloc((size_t)NBINS * 4);
    int* offs = (int*)alloc((size_t)(NBINS + 1) * 4);
    int* cur  = (int*)alloc((size_t)NBINS * 4);
    int* bsum = (int*)alloc(64 * 4);
    int* esrc = (int*)alloc((size_t)ETOT * 4);

    float* out = (float*)d_out;
    float* scores  = out;
    float* job_emb = out + NJ;
    float* qv      = out + NJ + (size_t)NJ * 128;

    // --- casts: x -> bf16, weights -> transposed bf16 ---
    {
        int tot4 = (NJ + NS) * SBERT / 4;
        k_cast_x<<<cdiv(tot4, 256), 256, 0, stream>>>(x_job, x_skill, xjob_b, xskill_b);
        CastTList L;
        L.m[0] = {W0_job, WtW0j, SBERT, 128};
        L.m[1] = {W0_skill, WtW0s, SBERT, 128};
        for (int lr = 0; lr < 6; ++lr)
            L.m[2 + lr] = {gat_Ws + (size_t)lr * 128 * 256, WtWs + (size_t)lr * 256 * 128, 128, 256};
        for (int i = 0; i < 4; ++i)
            L.m[8 + i] = {inter_W + (size_t)i * 256 * 128, WtI + (size_t)i * 128 * 256, 256, 128};
        L.m[12] = {Wjf, WtJf, 128, 128};
        k_castT<<<dim3(cdiv(SBERT * 128, 256), 13), 256, 0, stream>>>(L);
    }

    // --- precompute attention weight vectors ---
    k_wa<<<cdiv(2 * 1536, 256), 256, 0, stream>>>(gat_Ws, gat_as, gat_Wd, gat_ad, wsa, wda);

    // --- initial linear + LN + relu (bf16 MFMA) ---
    k_mgemm<3><<<dim3(cdiv(NJ, 128), 1), 256, 0, stream>>>(
        xjob_b, WtW0j, b0_job, g0_job, be0_job, xj, NJ, SBERT, 128);
    k_mgemm<3><<<dim3(cdiv(NS, 128), 1), 256, 0, stream>>>(
        xskill_b, WtW0s, b0_skill, g0_skill, be0_skill, xs, NS, SBERT, 128);

    // --- combined CSR build (layer-invariant) ---
    k_fill_i32<<<cdiv(NBINS, 256), 256, 0, stream>>>(deg, 0, NBINS);
    k_hist_all<<<cdiv(ETOT, 256), 256, 0, stream>>>(js_src, js_dst, sj_src, sj_dst,
                                                    ss_src, ss_dst, deg);
    k_scan1<<<SCAN_NB, SCAN_B, 0, stream>>>(deg, offs, bsum, NBINS);
    k_scan2<<<1, 64, 0, stream>>>(bsum, SCAN_NB);
    k_scan3<<<SCAN_NB, SCAN_B, 0, stream>>>(offs, bsum, NBINS, SCAN_NB);
    k_copy_i32<<<cdiv(NBINS, 256), 256, 0, stream>>>(offs, cur, NBINS);
    k_scatter_all<<<cdiv(ETOT, 256), 256, 0, stream>>>(js_src, js_dst, sj_src, sj_dst,
                                                       ss_src, ss_dst, cur, esrc);

    for (int l = 0; l < 2; ++l) {
        int l3 = l * 3;
        k_alpha_all<<<cdiv(NJ + NS, 4), 256, 0, stream>>>(xj, xs, wsa, wda, l3, aJ, aS);

        // o_s = GAT_js(xj->xs) + GAT_ss(xs->xs)
        k_mgemm<0><<<dim3(cdiv(NJ, 128), 2), 256, 0, stream>>>(
            xj, WtWs + (size_t)(l3 + 0) * 256 * 128, nullptr, nullptr, nullptr, hs, NJ, 128, 256);
        k_gather<<<cdiv(NS, 4), 256, 0, stream>>>(
            offs, esrc, aJ + 0, 4, aS + 2, 8, hs, gat_b + (size_t)(l3 + 0) * 256, os, NS, 0);

        k_mgemm<0><<<dim3(cdiv(NS, 128), 2), 256, 0, stream>>>(
            xs, WtWs + (size_t)(l3 + 2) * 256 * 128, nullptr, nullptr, nullptr, hs, NS, 128, 256);
        k_gather<<<cdiv(NS, 4), 256, 0, stream>>>(
            offs + NS + NJ, esrc, aS + 0, 8, aS + 6, 8, hs, gat_b + (size_t)(l3 + 2) * 256, os, NS, 1);

        // o_j = GAT_sj(xs->xj)
        k_mgemm<0><<<dim3(cdiv(NS, 128), 2), 256, 0, stream>>>(
            xs, WtWs + (size_t)(l3 + 1) * 256 * 128, nullptr, nullptr, nullptr, hs, NS, 128, 256);
        k_gather<<<cdiv(NJ, 4), 256, 0, stream>>>(
            offs + NS, esrc, aS + 4, 8, aJ + 2, 4, hs, gat_b + (size_t)(l3 + 1) * 256, oj, NJ, 0);

        // inter linears + relu (overwrite xj, xs)
        k_mgemm<2><<<dim3(cdiv(NJ, 128), 1), 256, 0, stream>>>(
            oj, WtI + (size_t)(l * 2 + 0) * 128 * 256, inter_b + (size_t)(l * 2 + 0) * 128,
            nullptr, nullptr, xj, NJ, 256, 128);
        k_mgemm<2><<<dim3(cdiv(NS, 128), 1), 256, 0, stream>>>(
            os, WtI + (size_t)(l * 2 + 1) * 128 * 256, inter_b + (size_t)(l * 2 + 1) * 128,
            nullptr, nullptr, xs, NS, 256, 128);
    }

    // final projections + scores
    k_mgemm<1><<<dim3(cdiv(NJ, 128), 1), 256, 0, stream>>>(
        xj, WtJf, bjf, nullptr, nullptr, job_emb, NJ, 128, 128);
    k_qvec<<<1, 128, 0, stream>>>(query, Wq, bq, qv);
    k_scores<<<cdiv(NJ, 4), 256, 0, stream>>>(job_emb, qv, scores, NJ);
}

// Round 4
// 563.662 us; speedup vs baseline: 2.6551x; 1.1998x over previous
//
#include <hip/hip_runtime.h>
#include <hip/hip_bf16.h>
#include <math.h>

#define NJ 30000
#define NS 12000
#define E_JS 300000
#define E_SJ 300000
#define E_SS 150000
#define ETOT (E_JS + E_SJ + E_SS + NS)   // 762000 incl. ss self loops
#define NBINS (NS + NJ + NS)             // 54000 combined dst bins
#define SBERT 384
#define HIDDEN 128
#define OUTD 128
#define SCAN_B 1024
#define SCAN_NB ((NBINS + SCAN_B - 1) / SCAN_B)   // 53

static inline int cdiv(int a, int b) { return (a + b - 1) / b; }

typedef __attribute__((ext_vector_type(8))) short bf8_t;
typedef __attribute__((ext_vector_type(4))) float f4_t;

__device__ inline float bf2f(unsigned short u) {
    union { unsigned int i; float f; } z; z.i = ((unsigned int)u) << 16; return z.f;
}
__device__ inline unsigned short f2bf(float f) {
    unsigned int x = __float_as_uint(f);
    unsigned int r = (x + 0x7fffu + ((x >> 16) & 1u)) >> 16;   // RNE
    return (unsigned short)r;
}

// ---------------------------------------------------------------------------
// Utility kernels
// ---------------------------------------------------------------------------
__global__ void k_fill_i32(int* __restrict__ p, int v, int n) {
    int i = blockIdx.x * 256 + threadIdx.x;
    if (i < n) p[i] = v;
}
__global__ void k_copy_i32(const int* __restrict__ a, int* __restrict__ b, int n) {
    int i = blockIdx.x * 256 + threadIdx.x;
    if (i < n) b[i] = a[i];
}

// ---------------------------------------------------------------------------
// cast fp32 x_job/x_skill -> bf16
// ---------------------------------------------------------------------------
__global__ void k_cast_x(const float* __restrict__ xj, const float* __restrict__ xs,
                         unsigned short* __restrict__ oj, unsigned short* __restrict__ os) {
    const int NJE = NJ * SBERT;
    const int TOT = (NJ + NS) * SBERT;
    int i4 = (blockIdx.x * 256 + threadIdx.x) * 4;
    if (i4 >= TOT) return;
    const float* src; unsigned short* dst; int off;
    if (i4 < NJE) { src = xj; dst = oj; off = i4; }
    else { src = xs; dst = os; off = i4 - NJE; }
    float4 v = *(const float4*)&src[off];
    ushort4 o; o.x = f2bf(v.x); o.y = f2bf(v.y); o.z = f2bf(v.z); o.w = f2bf(v.w);
    *(ushort4*)&dst[off] = o;
}

// ---------------------------------------------------------------------------
// batched weight transpose+cast: dst[n*K+k] = (bf16)src[k*N+n]
// ---------------------------------------------------------------------------
struct CastT { const float* src; unsigned short* dst; int K; int N; };
struct CastTList { CastT m[13]; };

__global__ void k_castT(CastTList L) {
    CastT c = L.m[blockIdx.y];
    int idx = blockIdx.x * 256 + threadIdx.x;
    int total = c.K * c.N;
    if (idx >= total) return;
    int n = idx / c.K, k = idx % c.K;
    c.dst[idx] = f2bf(c.src[(size_t)k * c.N + n]);
}

// ---------------------------------------------------------------------------
// Precompute ws_a / wd_a : wa[l,r][k][h] = sum_c W[l,r][k][h*128+c] * a[l,r][h][c]
// ---------------------------------------------------------------------------
__global__ void k_wa(const float* __restrict__ Ws, const float* __restrict__ as,
                     const float* __restrict__ Wd, const float* __restrict__ ad,
                     float* __restrict__ wsa, float* __restrict__ wda) {
    int id = blockIdx.x * 256 + threadIdx.x;   // 2 * 1536 total
    if (id >= 2 * 1536) return;
    int which = id / 1536;
    int r = id % 1536;
    int lr = r / 256;       // 0..5  (l*3 + rel)
    int kh = r % 256;
    int k = kh / 2, h = kh % 2;
    const float* W = which ? Wd : Ws;
    const float* a = which ? ad : as;
    const float* wrow = W + ((size_t)(lr * 128 + k)) * 256 + h * 128;
    const float* arow = a + (size_t)(lr * 2 + h) * 128;
    float acc = 0.f;
    for (int c = 0; c < 128; ++c) acc += wrow[c] * arow[c];
    (which ? wda : wsa)[lr * 256 + k * 2 + h] = acc;
}

// ---------------------------------------------------------------------------
// bf16 MFMA GEMM: Y[M,ldY](n0..n0+127) = X[M,K] @ Wt[n][k]^T
//   BM: 64 or 128 rows per block. 4 waves; wave covers BM/4 rows x 128 cols.
//   EPI: 0 none->bf16, 1 +bias->fp32, 2 +bias,relu->bf16, 3 +bias,LN,relu->bf16
// ---------------------------------------------------------------------------
template <int BM, int EPI>
__global__ __launch_bounds__(256) void k_mgemm(
    const unsigned short* __restrict__ X, const unsigned short* __restrict__ Wt,
    const float* __restrict__ bias, const float* __restrict__ gamma,
    const float* __restrict__ beta, void* __restrict__ Yv, int M, int K, int ldY) {
    constexpr int MT = BM / 64;          // 16-row m-tiles per wave
    __shared__ __align__(16) unsigned short Al[BM][40];
    __shared__ __align__(16) unsigned short Bl[128][40];
    const int t = threadIdx.x;
    const int wave = t >> 6, lane = t & 63;
    const int q = lane >> 4, c = lane & 15;
    const int row0 = blockIdx.x * BM;
    const int n0 = blockIdx.y * 128;

    f4_t acc[MT][8];
#pragma unroll
    for (int mt = 0; mt < MT; ++mt)
#pragma unroll
        for (int nt = 0; nt < 8; ++nt) acc[mt][nt] = (f4_t){0.f, 0.f, 0.f, 0.f};

    for (int k0 = 0; k0 < K; k0 += 32) {
#pragma unroll
        for (int idx = t; idx < (BM + 128) * 4; idx += 256) {
            int r = idx >> 2, cc = (idx & 3) * 8;
            if (r < BM) {
                int gr = row0 + r;
                uint4 va = (gr < M) ? *(const uint4*)&X[(size_t)gr * K + k0 + cc]
                                    : make_uint4(0u, 0u, 0u, 0u);
                *(uint4*)&Al[r][cc] = va;
            } else {
                int br = r - BM;
                *(uint4*)&Bl[br][cc] = *(const uint4*)&Wt[(size_t)(n0 + br) * K + k0 + cc];
            }
        }
        __syncthreads();
        bf8_t af[MT];
#pragma unroll
        for (int mt = 0; mt < MT; ++mt)
            af[mt] = *(const bf8_t*)&Al[wave * (BM / 4) + mt * 16 + c][q * 8];
#pragma unroll
        for (int nt = 0; nt < 8; ++nt) {
            bf8_t bfr = *(const bf8_t*)&Bl[nt * 16 + c][q * 8];
#pragma unroll
            for (int mt = 0; mt < MT; ++mt)
                acc[mt][nt] = __builtin_amdgcn_mfma_f32_16x16x32_bf16(af[mt], bfr, acc[mt][nt], 0, 0, 0);
        }
        __syncthreads();
    }

    float bcol[8], gcol[8], becol[8];
#pragma unroll
    for (int nt = 0; nt < 8; ++nt) {
        bcol[nt] = (EPI >= 1) ? bias[n0 + nt * 16 + c] : 0.f;
        if constexpr (EPI == 3) {
            gcol[nt] = gamma[nt * 16 + c];
            becol[nt] = beta[nt * 16 + c];
        }
    }

#pragma unroll
    for (int mt = 0; mt < MT; ++mt) {
#pragma unroll
        for (int r = 0; r < 4; ++r) {
            int grow = row0 + wave * (BM / 4) + mt * 16 + q * 4 + r;
            float v[8];
#pragma unroll
            for (int nt = 0; nt < 8; ++nt) v[nt] = acc[mt][nt][r] + bcol[nt];
            if constexpr (EPI == 3) {
                float s = 0.f, ss = 0.f;
#pragma unroll
                for (int nt = 0; nt < 8; ++nt) { s += v[nt]; ss += v[nt] * v[nt]; }
#pragma unroll
                for (int m = 8; m >= 1; m >>= 1) {
                    s += __shfl_xor(s, m, 64);
                    ss += __shfl_xor(ss, m, 64);
                }
                float mu = s * (1.f / 128.f);
                float var = ss * (1.f / 128.f) - mu * mu;
                float rs = rsqrtf(var + 1e-5f);
#pragma unroll
                for (int nt = 0; nt < 8; ++nt)
                    v[nt] = fmaxf((v[nt] - mu) * rs * gcol[nt] + becol[nt], 0.f);
            } else if constexpr (EPI == 2) {
#pragma unroll
                for (int nt = 0; nt < 8; ++nt) v[nt] = fmaxf(v[nt], 0.f);
            }
            if (grow < M) {
                if constexpr (EPI == 1) {
                    float* Y = (float*)Yv;
#pragma unroll
                    for (int nt = 0; nt < 8; ++nt)
                        Y[(size_t)grow * ldY + n0 + nt * 16 + c] = v[nt];
                } else {
                    unsigned short* Y = (unsigned short*)Yv;
#pragma unroll
                    for (int nt = 0; nt < 8; ++nt)
                        Y[(size_t)grow * ldY + n0 + nt * 16 + c] = f2bf(v[nt]);
                }
            }
        }
    }
}

// ---------------------------------------------------------------------------
// Per-layer alpha precompute (unchanged from round 3)
// ---------------------------------------------------------------------------
__global__ __launch_bounds__(256) void k_alpha_all(
    const unsigned short* __restrict__ xj, const unsigned short* __restrict__ xs,
    const float* __restrict__ wsa, const float* __restrict__ wda, int l3,
    float* __restrict__ aJ, float* __restrict__ aS) {
    int wave = threadIdx.x >> 6, lane = threadIdx.x & 63;
    int node = blockIdx.x * 4 + wave;
    if (node < NJ) {
        ushort2 xv = *(const ushort2*)&xj[(size_t)node * 128 + lane * 2];
        float x0 = bf2f(xv.x), x1 = bf2f(xv.y);
        float4 w0 = *(const float4*)&wsa[(size_t)(l3 + 0) * 256 + lane * 4];
        float4 w1 = *(const float4*)&wda[(size_t)(l3 + 1) * 256 + lane * 4];
        float p0 = x0 * w0.x + x1 * w0.z, p1 = x0 * w0.y + x1 * w0.w;
        float p2 = x0 * w1.x + x1 * w1.z, p3 = x0 * w1.y + x1 * w1.w;
#pragma unroll
        for (int m = 32; m >= 1; m >>= 1) {
            p0 += __shfl_xor(p0, m, 64); p1 += __shfl_xor(p1, m, 64);
            p2 += __shfl_xor(p2, m, 64); p3 += __shfl_xor(p3, m, 64);
        }
        if (lane == 0) {
            float4* o = (float4*)&aJ[(size_t)node * 4];
            *o = make_float4(p0, p1, p2, p3);
        }
    } else if (node < NJ + NS) {
        int n = node - NJ;
        ushort2 xv = *(const ushort2*)&xs[(size_t)n * 128 + lane * 2];
        float x0 = bf2f(xv.x), x1 = bf2f(xv.y);
        float4 wA = *(const float4*)&wsa[(size_t)(l3 + 2) * 256 + lane * 4];  // as ss
        float4 wB = *(const float4*)&wda[(size_t)(l3 + 0) * 256 + lane * 4];  // ad js
        float4 wC = *(const float4*)&wsa[(size_t)(l3 + 1) * 256 + lane * 4];  // as sj
        float4 wD = *(const float4*)&wda[(size_t)(l3 + 2) * 256 + lane * 4];  // ad ss
        float p0 = x0 * wA.x + x1 * wA.z, p1 = x0 * wA.y + x1 * wA.w;
        float p2 = x0 * wB.x + x1 * wB.z, p3 = x0 * wB.y + x1 * wB.w;
        float p4 = x0 * wC.x + x1 * wC.z, p5 = x0 * wC.y + x1 * wC.w;
        float p6 = x0 * wD.x + x1 * wD.z, p7 = x0 * wD.y + x1 * wD.w;
#pragma unroll
        for (int m = 32; m >= 1; m >>= 1) {
            p0 += __shfl_xor(p0, m, 64); p1 += __shfl_xor(p1, m, 64);
            p2 += __shfl_xor(p2, m, 64); p3 += __shfl_xor(p3, m, 64);
            p4 += __shfl_xor(p4, m, 64); p5 += __shfl_xor(p5, m, 64);
            p6 += __shfl_xor(p6, m, 64); p7 += __shfl_xor(p7, m, 64);
        }
        if (lane == 0) {
            float4* o = (float4*)&aS[(size_t)n * 8];
            o[0] = make_float4(p0, p1, p2, p3);
            o[1] = make_float4(p4, p5, p6, p7);
        }
    }
}

// ---------------------------------------------------------------------------
// Combined CSR over all relations (unchanged from round 3)
// ---------------------------------------------------------------------------
__device__ inline void edge_decode(int e, const int* js_src, const int* js_dst,
                                   const int* sj_src, const int* sj_dst,
                                   const int* ss_src, const int* ss_dst,
                                   int& src, int& bin) {
    if (e < E_JS) { src = js_src[e]; bin = js_dst[e]; }
    else if (e < E_JS + E_SJ) { int i = e - E_JS; src = sj_src[i]; bin = NS + sj_dst[i]; }
    else if (e < E_JS + E_SJ + E_SS) { int i = e - E_JS - E_SJ; src = ss_src[i]; bin = NS + NJ + ss_dst[i]; }
    else { int i = e - E_JS - E_SJ - E_SS; src = i; bin = NS + NJ + i; }
}

__global__ void k_hist_all(const int* __restrict__ js_src, const int* __restrict__ js_dst,
                           const int* __restrict__ sj_src, const int* __restrict__ sj_dst,
                           const int* __restrict__ ss_src, const int* __restrict__ ss_dst,
                           int* __restrict__ deg) {
    int e = blockIdx.x * 256 + threadIdx.x;
    if (e >= ETOT) return;
    int src, bin;
    edge_decode(e, js_src, js_dst, sj_src, sj_dst, ss_src, ss_dst, src, bin);
    atomicAdd(&deg[bin], 1);
}

__global__ void k_scatter_all(const int* __restrict__ js_src, const int* __restrict__ js_dst,
                              const int* __restrict__ sj_src, const int* __restrict__ sj_dst,
                              const int* __restrict__ ss_src, const int* __restrict__ ss_dst,
                              int* __restrict__ cur, int* __restrict__ esrc) {
    int e = blockIdx.x * 256 + threadIdx.x;
    if (e >= ETOT) return;
    int src, bin;
    edge_decode(e, js_src, js_dst, sj_src, sj_dst, ss_src, ss_dst, src, bin);
    int pos = atomicAdd(&cur[bin], 1);
    esrc[pos] = src;
}

__global__ void k_scan1(const int* __restrict__ deg, int* __restrict__ offs,
                        int* __restrict__ bsum, int n) {
    __shared__ int sd[SCAN_B];
    int b = blockIdx.x;
    int i = b * SCAN_B + threadIdx.x;
    int v = (i < n) ? deg[i] : 0;
    sd[threadIdx.x] = v;
    __syncthreads();
    for (int off = 1; off < SCAN_B; off <<= 1) {
        int t = (threadIdx.x >= (unsigned)off) ? sd[threadIdx.x - off] : 0;
        __syncthreads();
        sd[threadIdx.x] += t;
        __syncthreads();
    }
    if (i < n) offs[i] = sd[threadIdx.x] - v;   // block-local exclusive
    if (threadIdx.x == SCAN_B - 1) bsum[b] = sd[SCAN_B - 1];
}

__global__ void k_scan2(int* __restrict__ bsum, int nb) {
    int lane = threadIdx.x;   // 64 threads
    int v = (lane < nb) ? bsum[lane] : 0;
#pragma unroll
    for (int off = 1; off < 64; off <<= 1) {
        int t = __shfl_up(v, off, 64);
        if (lane >= off) v += t;
    }
    if (lane < nb) bsum[lane] = v;   // inclusive
}

__global__ void k_scan3(int* __restrict__ offs, const int* __restrict__ bsum, int n, int nb) {
    int b = blockIdx.x;
    int i = b * SCAN_B + threadIdx.x;
    int add = (b > 0) ? bsum[b - 1] : 0;
    if (i < n) offs[i] += add;
    if (i == 0) offs[n] = bsum[nb - 1];
}

// ---------------------------------------------------------------------------
// Fused gather + edge softmax, 4-way unrolled edge loop (clamped tail).
// wave per dst node; lane covers 4 cols of its head; per-lane den.
// hs has leading dim hsLd (bf16); pass hs pre-offset for column base.
// ---------------------------------------------------------------------------
__global__ __launch_bounds__(256) void k_gather(
    const int* __restrict__ offs, const int* __restrict__ esrc,
    const float* __restrict__ aS, int sStride,
    const float* __restrict__ aD, int dStride,
    const unsigned short* __restrict__ hs, int hsLd,
    const float* __restrict__ bias,
    unsigned short* __restrict__ out, int Nd, int accumulate) {
    int wave = threadIdx.x >> 6, lane = threadIdx.x & 63;
    int d = blockIdx.x * 4 + wave;
    if (d >= Nd) return;
    int c = lane * 4;
    int h = (c >= 128) ? 1 : 0;
    float ad = aD[(size_t)d * dStride + h];
    int beg = offs[d], end = offs[d + 1];
    float ax = 0.f, ay = 0.f, az = 0.f, aw = 0.f, den = 0.f;
    for (int j = beg; j < end; j += 4) {
        int j1 = j + 1 < end ? j + 1 : end - 1;
        int j2 = j + 2 < end ? j + 2 : end - 1;
        int j3 = j + 3 < end ? j + 3 : end - 1;
        int s0 = esrc[j], s1 = esrc[j1], s2 = esrc[j2], s3 = esrc[j3];
        float as0 = aS[(size_t)s0 * sStride + h];
        float as1 = aS[(size_t)s1 * sStride + h];
        float as2 = aS[(size_t)s2 * sStride + h];
        float as3 = aS[(size_t)s3 * sStride + h];
        ushort4 v0 = *(const ushort4*)&hs[(size_t)s0 * hsLd + c];
        ushort4 v1 = *(const ushort4*)&hs[(size_t)s1 * hsLd + c];
        ushort4 v2 = *(const ushort4*)&hs[(size_t)s2 * hsLd + c];
        ushort4 v3 = *(const ushort4*)&hs[(size_t)s3 * hsLd + c];
        float e0 = as0 + ad; e0 = e0 > 0.f ? e0 : 0.2f * e0;
        float e1 = as1 + ad; e1 = e1 > 0.f ? e1 : 0.2f * e1;
        float e2 = as2 + ad; e2 = e2 > 0.f ? e2 : 0.2f * e2;
        float e3 = as3 + ad; e3 = e3 > 0.f ? e3 : 0.2f * e3;
        float p0 = __expf(e0);
        float p1 = (j + 1 < end) ? __expf(e1) : 0.f;
        float p2 = (j + 2 < end) ? __expf(e2) : 0.f;
        float p3 = (j + 3 < end) ? __expf(e3) : 0.f;
        ax += p0 * bf2f(v0.x) + p1 * bf2f(v1.x) + p2 * bf2f(v2.x) + p3 * bf2f(v3.x);
        ay += p0 * bf2f(v0.y) + p1 * bf2f(v1.y) + p2 * bf2f(v2.y) + p3 * bf2f(v3.y);
        az += p0 * bf2f(v0.z) + p1 * bf2f(v1.z) + p2 * bf2f(v2.z) + p3 * bf2f(v3.z);
        aw += p0 * bf2f(v0.w) + p1 * bf2f(v1.w) + p2 * bf2f(v2.w) + p3 * bf2f(v3.w);
        den += p0 + p1 + p2 + p3;
    }
    float sc = 1.f / (den + 1e-16f);
    float4 b4 = *(const float4*)&bias[c];
    unsigned short* op = &out[(size_t)d * 256 + c];
    float o0 = ax * sc + b4.x, o1 = ay * sc + b4.y;
    float o2 = az * sc + b4.z, o3 = aw * sc + b4.w;
    if (accumulate) {
        ushort4 prev = *(ushort4*)op;
        o0 += bf2f(prev.x); o1 += bf2f(prev.y); o2 += bf2f(prev.z); o3 += bf2f(prev.w);
    }
    ushort4 o; o.x = f2bf(o0); o.y = f2bf(o1); o.z = f2bf(o2); o.w = f2bf(o3);
    *(ushort4*)op = o;
}

// ---------------------------------------------------------------------------
// q = query @ Wq + bq  (fp32)
// ---------------------------------------------------------------------------
__global__ void k_qvec(const float* __restrict__ query, const float* __restrict__ Wq,
                       const float* __restrict__ bq, float* __restrict__ qv) {
    int c = threadIdx.x;  // 128
    float acc = bq[c];
    for (int k = 0; k < SBERT; ++k) acc += query[k] * Wq[(size_t)k * 128 + c];
    qv[c] = acc;
}

// scores[r] = job_emb[r] . q   (wave per row, job_emb fp32)
__global__ __launch_bounds__(256) void k_scores(const float* __restrict__ jemb,
                                                const float* __restrict__ q,
                                                float* __restrict__ sc, int n) {
    int wave = threadIdx.x >> 6, lane = threadIdx.x & 63;
    int r = blockIdx.x * 4 + wave;
    if (r >= n) return;
    float2 a = *(const float2*)&jemb[(size_t)r * 128 + lane * 2];
    float2 b = *(const float2*)&q[lane * 2];
    float p = a.x * b.x + a.y * b.y;
#pragma unroll
    for (int m = 32; m >= 1; m >>= 1) p += __shfl_xor(p, m, 64);
    if (lane == 0) sc[r] = p;
}

// ---------------------------------------------------------------------------
extern "C" void kernel_launch(void* const* d_in, const int* in_sizes, int n_in,
                              void* d_out, int out_size, void* d_ws, size_t ws_size,
                              hipStream_t stream) {
    const float* x_job   = (const float*)d_in[0];
    const float* x_skill = (const float*)d_in[1];
    const int* js_src = (const int*)d_in[2];
    const int* js_dst = (const int*)d_in[3];
    const int* sj_src = (const int*)d_in[4];
    const int* sj_dst = (const int*)d_in[5];
    const int* ss_src = (const int*)d_in[6];
    const int* ss_dst = (const int*)d_in[7];
    const float* query    = (const float*)d_in[8];
    const float* W0_job   = (const float*)d_in[9];
    const float* b0_job   = (const float*)d_in[10];
    const float* g0_job   = (const float*)d_in[11];
    const float* be0_job  = (const float*)d_in[12];
    const float* W0_skill = (const float*)d_in[13];
    const float* b0_skill = (const float*)d_in[14];
    const float* g0_skill = (const float*)d_in[15];
    const float* be0_skill= (const float*)d_in[16];
    const float* gat_Ws = (const float*)d_in[17];
    const float* gat_Wd = (const float*)d_in[18];
    const float* gat_as = (const float*)d_in[19];
    const float* gat_ad = (const float*)d_in[20];
    const float* gat_b  = (const float*)d_in[21];
    const float* inter_W = (const float*)d_in[22];
    const float* inter_b = (const float*)d_in[23];
    const float* Wjf = (const float*)d_in[24];
    const float* bjf = (const float*)d_in[25];
    const float* Wq  = (const float*)d_in[26];
    const float* bq  = (const float*)d_in[27];

    // workspace carve (256B aligned bump allocator)
    char* w = (char*)d_ws;
    auto alloc = [&](size_t bytes) -> void* {
        void* p = (void*)w;
        w += (bytes + 255) & ~(size_t)255;
        return p;
    };
    typedef unsigned short u16;
    u16* xjob_b   = (u16*)alloc((size_t)NJ * SBERT * 2);
    u16* xskill_b = (u16*)alloc((size_t)NS * SBERT * 2);
    u16* xj  = (u16*)alloc((size_t)NJ * 128 * 2);
    u16* xs  = (u16*)alloc((size_t)NS * 128 * 2);
    u16* hs1 = (u16*)alloc((size_t)NJ * 256 * 2);   // job-side projection (js)
    u16* hs2 = (u16*)alloc((size_t)NS * 512 * 2);   // skill-side: [sj | ss]
    u16* oj  = (u16*)alloc((size_t)NJ * 256 * 2);
    u16* os  = (u16*)alloc((size_t)NS * 256 * 2);
    // transposed bf16 weights
    u16* WtW0j = (u16*)alloc((size_t)SBERT * 128 * 2);
    u16* WtW0s = (u16*)alloc((size_t)SBERT * 128 * 2);
    u16* WtWs  = (u16*)alloc((size_t)6 * 128 * 256 * 2);   // [lr][256][128]
    u16* WtI   = (u16*)alloc((size_t)4 * 256 * 128 * 2);   // [i][128][256]
    u16* WtJf  = (u16*)alloc((size_t)128 * 128 * 2);
    float* aJ = (float*)alloc((size_t)NJ * 4 * 4);
    float* aS = (float*)alloc((size_t)NS * 8 * 4);
    float* wsa = (float*)alloc(6 * 256 * 4);
    float* wda = (float*)alloc(6 * 256 * 4);
    int* deg  = (int*)alloc((size_t)NBINS * 4);
    int* offs = (int*)alloc((size_t)(NBINS + 1) * 4);
    int* cur  = (int*)alloc((size_t)NBINS * 4);
    int* bsum = (int*)alloc(64 * 4);
    int* esrc = (int*)alloc((size_t)ETOT * 4);

    float* out = (float*)d_out;
    float* scores  = out;
    float* job_emb = out + NJ;
    float* qv      = out + NJ + (size_t)NJ * 128;

    // --- casts: x -> bf16, weights -> transposed bf16 ---
    {
        int tot4 = (NJ + NS) * SBERT / 4;
        k_cast_x<<<cdiv(tot4, 256), 256, 0, stream>>>(x_job, x_skill, xjob_b, xskill_b);
        CastTList L;
        L.m[0] = {W0_job, WtW0j, SBERT, 128};
        L.m[1] = {W0_skill, WtW0s, SBERT, 128};
        for (int lr = 0; lr < 6; ++lr)
            L.m[2 + lr] = {gat_Ws + (size_t)lr * 128 * 256, WtWs + (size_t)lr * 256 * 128, 128, 256};
        for (int i = 0; i < 4; ++i)
            L.m[8 + i] = {inter_W + (size_t)i * 256 * 128, WtI + (size_t)i * 128 * 256, 256, 128};
        L.m[12] = {Wjf, WtJf, 128, 128};
        k_castT<<<dim3(cdiv(SBERT * 128, 256), 13), 256, 0, stream>>>(L);
    }

    // --- precompute attention weight vectors ---
    k_wa<<<cdiv(2 * 1536, 256), 256, 0, stream>>>(gat_Ws, gat_as, gat_Wd, gat_ad, wsa, wda);

    // --- initial linear + LN + relu (bf16 MFMA) ---
    k_mgemm<64, 3><<<dim3(cdiv(NJ, 64), 1), 256, 0, stream>>>(
        xjob_b, WtW0j, b0_job, g0_job, be0_job, xj, NJ, SBERT, 128);
    k_mgemm<64, 3><<<dim3(cdiv(NS, 64), 1), 256, 0, stream>>>(
        xskill_b, WtW0s, b0_skill, g0_skill, be0_skill, xs, NS, SBERT, 128);

    // --- combined CSR build (layer-invariant) ---
    k_fill_i32<<<cdiv(NBINS, 256), 256, 0, stream>>>(deg, 0, NBINS);
    k_hist_all<<<cdiv(ETOT, 256), 256, 0, stream>>>(js_src, js_dst, sj_src, sj_dst,
                                                    ss_src, ss_dst, deg);
    k_scan1<<<SCAN_NB, SCAN_B, 0, stream>>>(deg, offs, bsum, NBINS);
    k_scan2<<<1, 64, 0, stream>>>(bsum, SCAN_NB);
    k_scan3<<<SCAN_NB, SCAN_B, 0, stream>>>(offs, bsum, NBINS, SCAN_NB);
    k_copy_i32<<<cdiv(NBINS, 256), 256, 0, stream>>>(offs, cur, NBINS);
    k_scatter_all<<<cdiv(ETOT, 256), 256, 0, stream>>>(js_src, js_dst, sj_src, sj_dst,
                                                       ss_src, ss_dst, cur, esrc);

    for (int l = 0; l < 2; ++l) {
        int l3 = l * 3;
        k_alpha_all<<<cdiv(NJ + NS, 4), 256, 0, stream>>>(xj, xs, wsa, wda, l3, aJ, aS);

        // projections: hs1 = xj @ Ws[js]; hs2 = xs @ [Ws[sj] | Ws[ss]] (N=512)
        k_mgemm<64, 0><<<dim3(cdiv(NJ, 64), 2), 256, 0, stream>>>(
            xj, WtWs + (size_t)(l3 + 0) * 256 * 128, nullptr, nullptr, nullptr, hs1, NJ, 128, 256);
        k_mgemm<64, 0><<<dim3(cdiv(NS, 64), 4), 256, 0, stream>>>(
            xs, WtWs + (size_t)(l3 + 1) * 256 * 128, nullptr, nullptr, nullptr, hs2, NS, 128, 512);

        // o_s = GAT_js(xj->xs) + GAT_ss(xs->xs)
        k_gather<<<cdiv(NS, 4), 256, 0, stream>>>(
            offs, esrc, aJ + 0, 4, aS + 2, 8, hs1, 256,
            gat_b + (size_t)(l3 + 0) * 256, os, NS, 0);
        k_gather<<<cdiv(NS, 4), 256, 0, stream>>>(
            offs + NS + NJ, esrc, aS + 0, 8, aS + 6, 8, hs2 + 256, 512,
            gat_b + (size_t)(l3 + 2) * 256, os, NS, 1);
        // o_j = GAT_sj(xs->xj)
        k_gather<<<cdiv(NJ, 4), 256, 0, stream>>>(
            offs + NS, esrc, aS + 4, 8, aJ + 2, 4, hs2, 512,
            gat_b + (size_t)(l3 + 1) * 256, oj, NJ, 0);

        // inter linears + relu (overwrite xj, xs)
        k_mgemm<64, 2><<<dim3(cdiv(NJ, 64), 1), 256, 0, stream>>>(
            oj, WtI + (size_t)(l * 2 + 0) * 128 * 256, inter_b + (size_t)(l * 2 + 0) * 128,
            nullptr, nullptr, xj, NJ, 256, 128);
        k_mgemm<64, 2><<<dim3(cdiv(NS, 64), 1), 256, 0, stream>>>(
            os, WtI + (size_t)(l * 2 + 1) * 128 * 256, inter_b + (size_t)(l * 2 + 1) * 128,
            nullptr, nullptr, xs, NS, 256, 128);
    }

    // final projections + scores
    k_mgemm<64, 1><<<dim3(cdiv(NJ, 64), 1), 256, 0, stream>>>(
        xj, WtJf, bjf, nullptr, nullptr, job_emb, NJ, 128, 128);
    k_qvec<<<1, 128, 0, stream>>>(query, Wq, bq, qv);
    k_scores<<<cdiv(NJ, 4), 256, 0, stream>>>(job_emb, qv, scores, NJ);
}